// Round 13
// baseline (3087.374 us; speedup 1.0000x reference)
//
#include <hip/hip_runtime.h>
#include <hip/hip_bf16.h>

#define BB 128
#define SS 16
#define EE 512
#define RR 500
#define G4 2048          // 4*E
#define OUT0 64128       // B*501 : scores chunk first
#define NSC 501          // R+1
#define NPAIR 2047       // uniform pair rows m=0..2046 (p==15 junk, never read)
#define NSU 1012         // 500 scores | 512 u

__device__ __forceinline__ float sigm(float x) { return 1.f / (1.f + expf(-x)); }

// ================= device-global pipeline buffers =================
__device__ float g_blstm[G4];
__device__ float g_fcw[EE + 4];          // fc_w, fc_b at [EE]
__device__ float g_qbias[1024];          // fcq_b | fck_b
__device__ float g_Krel[RR * EE];
__device__ float g_cur[BB * SS * EE];    // strided rows m = b*16 + j
__device__ float g_G[BB * SS * G4];      // persistent, shifted incrementally
__device__ float g_h1[BB * SS * EE];
__device__ float g_c1[BB * SS * EE];
__device__ float g_h2[BB * SS * EE];     // pair p at row b*16+p
__device__ float g_g2[BB * SS * G4];     // init scratch; first 256 rows reused per-iter
__device__ float g_sc[BB * SS];
__device__ float g_ent[BB * SS];
__device__ int   g_sel[BB];
// attention precomputes + fused buffers
__device__ float g_fckwT[EE * EE];
__device__ float g_W2[RR * EE];          // W2[k,e] = sum_e' Krel[k,e'] fcq[e',e]
__device__ float g_Mx[EE * EE];          // Mx[f,e] = sum_e' fcq[e',e] fck[e',f]
__device__ float g_c2[RR + 4];           // c2[k] = Krel[k,:]·bq
__device__ float g_v1[EE];               // v1[e] = fck^T bq + fcq^T bk
__device__ float g_c0[1];                // bq·bk
__device__ float g_su[BB * NSU];         // per-iter: scores | u

// ================= setup =================
__global__ void k_prep(const float* __restrict__ bih, const float* __restrict__ bhh,
                       const float* __restrict__ fcwv, const float* __restrict__ fcbv,
                       const float* __restrict__ fcqb, const float* __restrict__ fckb) {
    int i = blockIdx.x * blockDim.x + threadIdx.x;
    if (i < G4) g_blstm[i] = bih[i] + bhh[i];
    if (i < EE) {
        g_fcw[i] = fcwv[i];
        g_qbias[i] = fcqb[i];
        g_qbias[EE + i] = fckb[i];
    }
    if (i == 0) g_fcw[EE] = fcbv[0];
}

__global__ void k_gather(const int* __restrict__ tok, const float* __restrict__ emb) {
    int i = blockIdx.x * blockDim.x + threadIdx.x;
    if (i >= BB * SS * EE) return;
    int e = i & (EE - 1);
    int r = i >> 9;
    int t = tok[r];
    g_cur[i] = emb[(size_t)t * EE + e];
}

__global__ void k_tr(const float* __restrict__ fckw) {
    int i = blockIdx.x * blockDim.x + threadIdx.x;   // 512*512
    if (i >= EE * EE) return;
    int ep = i >> 9;
    int f = i & (EE - 1);
    g_fckwT[(size_t)f * EE + ep] = fckw[(size_t)ep * EE + f];
}

// c2 / v1 / c0 precompute
__global__ __launch_bounds__(512) void k_vprep(const float* __restrict__ fcqw, const float* __restrict__ fckw) {
    __shared__ float sh[512];
    int t = threadIdx.x;
    int blk = blockIdx.x;
    if (blk == 0) {
        float acc = 0.f;
        for (int ep = 0; ep < EE; ep++)
            acc += g_qbias[ep] * fckw[(size_t)ep * EE + t] + g_qbias[EE + ep] * fcqw[(size_t)ep * EE + t];
        g_v1[t] = acc;
    } else if (blk == 1) {
        sh[t] = g_qbias[t] * g_qbias[EE + t];
        __syncthreads();
        for (int s = 256; s > 0; s >>= 1) { if (t < s) sh[t] += sh[t + s]; __syncthreads(); }
        if (t == 0) g_c0[0] = sh[0];
    } else {
        int k = blk - 2;
        sh[t] = g_Krel[(size_t)k * EE + t] * g_qbias[t];
        __syncthreads();
        for (int s = 256; s > 0; s >>= 1) { if (t < s) sh[t] += sh[t + s]; __syncthreads(); }
        if (t == 0) g_c2[k] = sh[0];
    }
}

// ================= 64x64 tile GEMM core (init/setup GEMMs) =================
#define UM 64
#define UN 64
#define UK 32
__device__ __forceinline__ void gemm64(
    const float* __restrict__ A, int lda,
    const float* __restrict__ W, int ldw, int wtrans,
    const float* __restrict__ bias, const float* __restrict__ Dadd, int ldd,
    float* __restrict__ C, int ldc, int M, int N, int K)
{
    __shared__ float As[UM][UK + 1];
    __shared__ float Ws[UN][UK + 1];
    int tid = threadIdx.x;
    int mt = blockIdx.y * UM;
    int nt = blockIdx.x * UN;
    int tr = tid >> 4;       // 0..15
    int tc = tid & 15;       // 0..15
    float acc[4][4] = {{0,0,0,0},{0,0,0,0},{0,0,0,0},{0,0,0,0}};

    int ea = tid * 8;        // 64x32 = 2048 elems / 256 thr
    int ra = ea >> 5;        // 0..63
    int ka = ea & 31;        // 0,8,16,24
    int gmA = mt + ra;
    bool rokA = gmA < M;
    int gnW = nt + ra;
    bool rokW = gnW < N;

    for (int kt = 0; kt < K; kt += UK) {
        #pragma unroll
        for (int i = 0; i < 8; i++) {
            int gk = kt + ka + i;
            As[ra][ka + i] = (rokA && gk < K) ? A[(size_t)gmA * lda + gk] : 0.f;
            float wv = 0.f;
            if (rokW && gk < K)
                wv = wtrans ? W[(size_t)gk * ldw + gnW] : W[(size_t)gnW * ldw + gk];
            Ws[ra][ka + i] = wv;
        }
        __syncthreads();
        #pragma unroll
        for (int kk = 0; kk < UK; kk++) {
            float a0 = As[4 * tr + 0][kk], a1 = As[4 * tr + 1][kk];
            float a2 = As[4 * tr + 2][kk], a3 = As[4 * tr + 3][kk];
            float w0 = Ws[4 * tc + 0][kk], w1 = Ws[4 * tc + 1][kk];
            float w2 = Ws[4 * tc + 2][kk], w3 = Ws[4 * tc + 3][kk];
            acc[0][0] += a0 * w0; acc[0][1] += a0 * w1; acc[0][2] += a0 * w2; acc[0][3] += a0 * w3;
            acc[1][0] += a1 * w0; acc[1][1] += a1 * w1; acc[1][2] += a1 * w2; acc[1][3] += a1 * w3;
            acc[2][0] += a2 * w0; acc[2][1] += a2 * w1; acc[2][2] += a2 * w2; acc[2][3] += a2 * w3;
            acc[3][0] += a3 * w0; acc[3][1] += a3 * w1; acc[3][2] += a3 * w2; acc[3][3] += a3 * w3;
        }
        __syncthreads();
    }
    #pragma unroll
    for (int i = 0; i < 4; i++) {
        int gm = mt + 4 * tr + i;
        if (gm >= M) continue;
        #pragma unroll
        for (int j = 0; j < 4; j++) {
            int gn = nt + 4 * tc + j;
            if (gn >= N) continue;
            float v = acc[i][j];
            if (bias) v += bias[gn];
            if (Dadd) v += Dadd[(size_t)gm * ldd + gn];
            C[(size_t)gm * ldc + gn] = v;
        }
    }
}

__global__ __launch_bounds__(256) void kg_Krel(const float* __restrict__ emb, const float* __restrict__ fckw) {
    gemm64(emb, EE, fckw, EE, 0, g_qbias + EE, nullptr, 0, g_Krel, EE, RR, EE, EE);
}
__global__ __launch_bounds__(256) void kg_W2(const float* __restrict__ fcqw) {
    gemm64(g_Krel, EE, fcqw, EE, 1, nullptr, nullptr, 0, g_W2, EE, RR, EE, EE);
}
__global__ __launch_bounds__(256) void kg_Mx(const float* __restrict__ fcqw) {
    gemm64(g_fckwT, EE, fcqw, EE, 1, nullptr, nullptr, 0, g_Mx, EE, EE, EE, EE);
}
__global__ __launch_bounds__(256) void kg_G(const float* __restrict__ wih) {
    gemm64(g_cur, EE, wih, EE, 0, g_blstm, nullptr, 0, g_G, G4, BB * SS, G4, EE);
}
__global__ __launch_bounds__(256) void kg_g2(const float* __restrict__ whh) {
    gemm64(g_h1, EE, whh, EE, 0, nullptr, g_G + G4, G4, g_g2, G4, NPAIR, G4, EE);
}

// ================= 32x64 tile core constants (per-iter GEMMs) =================
#define TM 32
#define TN 64
#define TK 32

// ---- fused argmax + scores|u GEMM: A row = h2[b*16+sel[b]]; N=1012 ----
__global__ __launch_bounds__(256) void kg_su(int P) {
    __shared__ float As[TM][TK + 1];
    __shared__ float Ws[TN][TK + 1];
    __shared__ int s_sel[TM];
    int tid = threadIdx.x;
    int mt = blockIdx.y * TM;
    int nt = blockIdx.x * TN;
    int tr = tid >> 4;
    int tc = tid & 15;
    float acc[2][4] = {{0.f,0.f,0.f,0.f},{0.f,0.f,0.f,0.f}};

    if (tid < TM) {
        int b = mt + tid;                    // M = BB exact
        float best = -1e30f; int bi = 0;
        for (int p = 0; p < P; p++) {
            float v = g_sc[b * SS + p];
            if (v > best) { best = v; bi = p; }
        }
        s_sel[tid] = bi;
        if (blockIdx.x == 0) g_sel[b] = bi;
    }
    __syncthreads();

    int ea = tid * 4;
    int ra = ea >> 5;
    int ka = ea & 31;
    int gmA = mt + ra;
    int physA = gmA * SS + s_sel[ra];
    int ew = tid * 8;
    int rw = ew >> 5;
    int kw = ew & 31;
    int gnW = nt + rw;
    bool rokW = gnW < NSU;
    const float* Wrow = nullptr;
    if (rokW) Wrow = (gnW < RR) ? (g_W2 + (size_t)gnW * EE) : (g_Mx + (size_t)(gnW - RR) * EE);

    for (int kt = 0; kt < EE; kt += TK) {
        #pragma unroll
        for (int i = 0; i < 4; i++)
            As[ra][ka + i] = g_h2[(size_t)physA * EE + kt + ka + i];
        #pragma unroll
        for (int i = 0; i < 8; i++)
            Ws[rw][kw + i] = rokW ? Wrow[kt + kw + i] : 0.f;
        __syncthreads();
        #pragma unroll
        for (int kk = 0; kk < TK; kk++) {
            float a0 = As[2 * tr][kk];
            float a1 = As[2 * tr + 1][kk];
            float w0 = Ws[4 * tc + 0][kk];
            float w1 = Ws[4 * tc + 1][kk];
            float w2 = Ws[4 * tc + 2][kk];
            float w3 = Ws[4 * tc + 3][kk];
            acc[0][0] += a0 * w0; acc[0][1] += a0 * w1; acc[0][2] += a0 * w2; acc[0][3] += a0 * w3;
            acc[1][0] += a1 * w0; acc[1][1] += a1 * w1; acc[1][2] += a1 * w2; acc[1][3] += a1 * w3;
        }
        __syncthreads();
    }
    #pragma unroll
    for (int i = 0; i < 2; i++) {
        int gm = mt + 2 * tr + i;
        #pragma unroll
        for (int j = 0; j < 4; j++) {
            int gn = nt + 4 * tc + j;
            if (gn >= NSU) continue;
            g_su[(size_t)gm * NSU + gn] = acc[i][j] + (gn < RR ? g_c2[gn] : 0.f);
        }
    }
}

// ---- incremental GEMM: recompute G row (b*16+sel[b]); M=BB ----
__global__ __launch_bounds__(256) void kg_Gi(const float* __restrict__ wih) {
    __shared__ float As[TM][TK + 1];
    __shared__ float Ws[TN][TK + 1];
    int tid = threadIdx.x;
    int mt = blockIdx.y * TM;
    int nt = blockIdx.x * TN;
    int tr = tid >> 4;
    int tc = tid & 15;
    float acc[2][4] = {{0.f,0.f,0.f,0.f},{0.f,0.f,0.f,0.f}};

    int ea = tid * 4;
    int ra = ea >> 5;
    int ka = ea & 31;
    int gmA = mt + ra;
    int physA = gmA * SS + g_sel[gmA];
    int ew = tid * 8;
    int rw = ew >> 5;
    int kw = ew & 31;
    int gnW = nt + rw;

    for (int kt = 0; kt < EE; kt += TK) {
        #pragma unroll
        for (int i = 0; i < 4; i++)
            As[ra][ka + i] = g_cur[(size_t)physA * EE + kt + ka + i];
        #pragma unroll
        for (int i = 0; i < 8; i++)
            Ws[rw][kw + i] = wih[(size_t)gnW * EE + kt + kw + i];
        __syncthreads();
        #pragma unroll
        for (int kk = 0; kk < TK; kk++) {
            float a0 = As[2 * tr][kk];
            float a1 = As[2 * tr + 1][kk];
            float w0 = Ws[4 * tc + 0][kk];
            float w1 = Ws[4 * tc + 1][kk];
            float w2 = Ws[4 * tc + 2][kk];
            float w3 = Ws[4 * tc + 3][kk];
            acc[0][0] += a0 * w0; acc[0][1] += a0 * w1; acc[0][2] += a0 * w2; acc[0][3] += a0 * w3;
            acc[1][0] += a1 * w0; acc[1][1] += a1 * w1; acc[1][2] += a1 * w2; acc[1][3] += a1 * w3;
        }
        __syncthreads();
    }
    #pragma unroll
    for (int i = 0; i < 2; i++) {
        int gm = mt + 2 * tr + i;
        int phys = gm * SS + g_sel[gm];
        #pragma unroll
        for (int j = 0; j < 4; j++) {
            int gn = nt + 4 * tc + j;
            g_G[(size_t)phys * G4 + gn] = acc[i][j] + g_blstm[gn];
        }
    }
}

// ---- incremental GEMM: g2 for 2 pairs/batch; M=2*BB; h1/c1[sel] computed on the fly ----
__global__ __launch_bounds__(256) void kg_g2i(const float* __restrict__ whh) {
    __shared__ float As[TM][TK + 1];
    __shared__ float Ws[TN][TK + 1];
    int tid = threadIdx.x;
    int mt = blockIdx.y * TM;
    int nt = blockIdx.x * TN;
    int tr = tid >> 4;
    int tc = tid & 15;
    float acc[2][4] = {{0.f,0.f,0.f,0.f},{0.f,0.f,0.f,0.f}};
    bool nt0 = (blockIdx.x == 0);

    int ea = tid * 4;
    int ra = ea >> 5;
    int ka = ea & 31;
    int gmA = mt + ra;                       // compact pair index (M=256)
    int bA = gmA >> 1;
    int tpA = gmA & 1;
    int sA = g_sel[bA];
    int hrow = bA * SS + max(sA - 1, 0);     // tpair0 A source (h1, old)
    size_t Grow = (size_t)(bA * SS + sA) * G4;   // tpair1 A source (G gates, new)
    int ew = tid * 8;
    int rw = ew >> 5;
    int kw = ew & 31;
    int gnW = nt + rw;

    for (int kt = 0; kt < EE; kt += TK) {
        if (tpA) {
            #pragma unroll
            for (int i = 0; i < 4; i++) {
                int gk = kt + ka + i;
                float gi = g_G[Grow + gk];
                float gg = g_G[Grow + 1024 + gk];
                float go = g_G[Grow + 1536 + gk];
                float c = sigm(gi) * tanhf(gg);
                float h = sigm(go) * tanhf(c);
                if (nt0) {
                    g_c1[(size_t)(bA * SS + sA) * EE + gk] = c;
                    g_h1[(size_t)(bA * SS + sA) * EE + gk] = h;
                }
                As[ra][ka + i] = h;
            }
        } else {
            #pragma unroll
            for (int i = 0; i < 4; i++)
                As[ra][ka + i] = g_h1[(size_t)hrow * EE + kt + ka + i];
        }
        #pragma unroll
        for (int i = 0; i < 8; i++)
            Ws[rw][kw + i] = whh[(size_t)gnW * EE + kt + kw + i];
        __syncthreads();
        #pragma unroll
        for (int kk = 0; kk < TK; kk++) {
            float a0 = As[2 * tr][kk];
            float a1 = As[2 * tr + 1][kk];
            float w0 = Ws[4 * tc + 0][kk];
            float w1 = Ws[4 * tc + 1][kk];
            float w2 = Ws[4 * tc + 2][kk];
            float w3 = Ws[4 * tc + 3][kk];
            acc[0][0] += a0 * w0; acc[0][1] += a0 * w1; acc[0][2] += a0 * w2; acc[0][3] += a0 * w3;
            acc[1][0] += a1 * w0; acc[1][1] += a1 * w1; acc[1][2] += a1 * w2; acc[1][3] += a1 * w3;
        }
        __syncthreads();
    }
    #pragma unroll
    for (int i = 0; i < 2; i++) {
        int gm = mt + 2 * tr + i;
        int b = gm >> 1;
        int p = (gm & 1) ? g_sel[b] : max(g_sel[b] - 1, 0);
        size_t drow = (size_t)(b * SS + p + 1) * G4;   // + G[left+1]
        #pragma unroll
        for (int j = 0; j < 4; j++) {
            int gn = nt + 4 * tc + j;
            g_g2[(size_t)gm * G4 + gn] = acc[i][j] + g_G[drow + gn];
        }
    }
}

// ================= LSTM elementwise (init) =================
__global__ void k_h1() {
    int idx = blockIdx.x * blockDim.x + threadIdx.x;
    if (idx >= BB * SS * EE) return;
    int m = idx >> 9;
    int e = idx & (EE - 1);
    const float* g = g_G + (size_t)m * G4;
    float c = sigm(g[e]) * tanhf(g[1024 + e]);
    g_c1[idx] = c;
    g_h1[idx] = sigm(g[1536 + e]) * tanhf(c);
}

__global__ __launch_bounds__(256) void k_h2() {
    int m = blockIdx.x;                 // 0..2046
    const float* g = g_g2 + (size_t)m * G4;
    __shared__ float red[256];
    float part = 0.f;
    for (int e = threadIdx.x; e < EE; e += 256) {
        float c = sigm(g[512 + e]) * g_c1[(size_t)m * EE + e] + sigm(g[e]) * tanhf(g[1024 + e]);
        float h = sigm(g[1536 + e]) * tanhf(c);
        g_h2[(size_t)m * EE + e] = h;
        part += h * g_fcw[e];
    }
    red[threadIdx.x] = part;
    __syncthreads();
    for (int s = 128; s > 0; s >>= 1) {
        if (threadIdx.x < s) red[threadIdx.x] += red[threadIdx.x + s];
        __syncthreads();
    }
    if (threadIdx.x == 0) g_sc[m] = sigm(red[0] + g_fcw[EE]);
}

// per-iter h2/sc for the 2 candidate pairs (c1[sel] written by kg_g2i)
__global__ __launch_bounds__(256) void k_h2i(int L) {
    int m = blockIdx.x;                 // 0..255
    int b = m >> 1;
    int t = m & 1;
    int s = g_sel[b];
    int p = s - 1 + t;
    bool valid = t == 0 ? (s >= 1) : (s <= L - 3);
    if (!valid) return;
    const float* g = g_g2 + (size_t)m * G4;
    int cr = b * SS + p;
    __shared__ float red[256];
    float part = 0.f;
    for (int e = threadIdx.x; e < EE; e += 256) {
        float c = sigm(g[512 + e]) * g_c1[(size_t)cr * EE + e] + sigm(g[e]) * tanhf(g[1024 + e]);
        float h = sigm(g[1536 + e]) * tanhf(c);
        g_h2[(size_t)cr * EE + e] = h;
        part += h * g_fcw[e];
    }
    red[threadIdx.x] = part;
    __syncthreads();
    for (int ss = 128; ss > 0; ss >>= 1) {
        if (threadIdx.x < ss) red[threadIdx.x] += red[threadIdx.x + ss];
        __syncthreads();
    }
    if (threadIdx.x == 0) g_sc[cr] = sigm(red[0] + g_fcw[EE]);
}

// ================= fused softmax + entropy + merged + shift (+final output) =================
__global__ __launch_bounds__(512) void k_smu(int col, int finalFlag, int L,
                                             const float* __restrict__ emb, float* __restrict__ out) {
    int b = blockIdx.x;
    int t = threadIdx.x;      // 0..511
    __shared__ float sh[512];
    __shared__ float srow[NSC];
    __shared__ float s_p500;
    const float* su = g_su + (size_t)b * NSU;
    int s = g_sel[b];
    const float* h2row = g_h2 + (size_t)(b * SS + s) * EE;
    const float isq = 0.044194173824159216f;   // 1/sqrt(512)

    float hv = h2row[t];
    sh[t] = hv * (su[RR + t] + g_v1[t]);
    __syncthreads();
    for (int ss = 256; ss > 0; ss >>= 1) { if (t < ss) sh[t] += sh[t + ss]; __syncthreads(); }
    if (t == 0) srow[RR] = (sh[0] + g_c0[0]) * isq;
    __syncthreads();
    if (t < RR) srow[t] = su[t] * isq;
    __syncthreads();
    float mx = (t < NSC) ? srow[t] : -1e30f;
    sh[t] = mx; __syncthreads();
    for (int ss = 256; ss > 0; ss >>= 1) { if (t < ss) sh[t] = fmaxf(sh[t], sh[t + ss]); __syncthreads(); }
    mx = sh[0]; __syncthreads();
    float zp = (t < NSC) ? expf(srow[t] - mx) : 0.f;
    sh[t] = zp; __syncthreads();
    for (int ss = 256; ss > 0; ss >>= 1) { if (t < ss) sh[t] += sh[t + ss]; __syncthreads(); }
    float lse = mx + logf(sh[0]);
    __syncthreads();
    float p = (t < NSC) ? expf(srow[t] - lse) : 0.f;
    float ep = (t < NSC) ? p * (lse - srow[t]) : 0.f;
    if (finalFlag && t < NSC) out[(size_t)b * NSC + t] = srow[t];
    sh[t] = ep; __syncthreads();
    for (int ss = 256; ss > 0; ss >>= 1) { if (t < ss) sh[t] += sh[t + ss]; __syncthreads(); }
    if (finalFlag) {
        // loss region: cols 0..13 from g_ent, col 14 = 0, col 15 = this entropy
        if (t < 16) {
            float v = (t == 15) ? sh[0] : ((t == 14) ? 0.f : g_ent[b * SS + t]);
            out[OUT0 + b * 16 + t] = v;
        }
        return;
    }
    if (t == 0) g_ent[b * SS + col] = sh[0];

    __syncthreads();
    if (t < NSC) srow[t] = p;            // prob in place
    if (t == RR) s_p500 = p;
    __syncthreads();
    float macc = 0.f;
    #pragma unroll 4
    for (int k = 0; k < RR; k++) macc += srow[k] * emb[(size_t)k * EE + t];
    float newv = macc + s_p500 * hv;
    size_t base = (size_t)b * SS * EE;
    size_t gbase = (size_t)b * SS * G4;
    for (int j = s + 1; j <= L - 2; j++) {
        g_cur[base + (size_t)j * EE + t] = g_cur[base + (size_t)(j + 1) * EE + t];
        g_h1 [base + (size_t)j * EE + t] = g_h1 [base + (size_t)(j + 1) * EE + t];
        g_c1 [base + (size_t)j * EE + t] = g_c1 [base + (size_t)(j + 1) * EE + t];
        #pragma unroll
        for (int q = 0; q < 4; q++)
            g_G[gbase + (size_t)j * G4 + t + q * 512] = g_G[gbase + (size_t)(j + 1) * G4 + t + q * 512];
    }
    g_cur[base + (size_t)s * EE + t] = newv;
    for (int pp = s + 1; pp <= L - 3; pp++)
        g_h2[base + (size_t)pp * EE + t] = g_h2[base + (size_t)(pp + 1) * EE + t];
    if (t == 0)
        for (int pp = s + 1; pp <= L - 3; pp++) g_sc[b * SS + pp] = g_sc[b * SS + pp + 1];
}

// ================= host launch =================
extern "C" void kernel_launch(void* const* d_in, const int* in_sizes, int n_in,
                              void* d_out, int out_size, void* d_ws, size_t ws_size,
                              hipStream_t stream) {
    const int*   tokens = (const int*)d_in[0];
    const float* emb    = (const float*)d_in[1];
    const float* wih    = (const float*)d_in[2];
    const float* whh    = (const float*)d_in[3];
    const float* bih    = (const float*)d_in[4];
    const float* bhh    = (const float*)d_in[5];
    const float* fcwv   = (const float*)d_in[6];
    const float* fcbv   = (const float*)d_in[7];
    const float* fcqw   = (const float*)d_in[8];
    const float* fcqb   = (const float*)d_in[9];
    const float* fckw   = (const float*)d_in[10];
    const float* fckb   = (const float*)d_in[11];
    float* out = (float*)d_out;

    auto grid32 = [](int M, int N) { return dim3((unsigned)((N + TN - 1) / TN), (unsigned)((M + TM - 1) / TM)); };
    auto grid64 = [](int M, int N) { return dim3((unsigned)((N + UN - 1) / UN), (unsigned)((M + UM - 1) / UM)); };

    // ---- setup + attention precomputes (once) ----
    k_prep<<<dim3(8), dim3(256), 0, stream>>>(bih, bhh, fcwv, fcbv, fcqb, fckb);
    kg_Krel<<<grid64(RR, EE), dim3(256), 0, stream>>>(emb, fckw);
    k_tr<<<dim3((EE * EE + 255) / 256), dim3(256), 0, stream>>>(fckw);
    kg_W2<<<grid64(RR, EE), dim3(256), 0, stream>>>(fcqw);
    kg_Mx<<<grid64(EE, EE), dim3(256), 0, stream>>>(fcqw);
    k_vprep<<<dim3(502), dim3(512), 0, stream>>>(fcqw, fckw);
    k_gather<<<dim3((BB * SS * EE + 255) / 256), dim3(256), 0, stream>>>(tokens, emb);

    // ---- initial full LSTM pass (once) ----
    kg_G<<<grid64(BB * SS, G4), dim3(256), 0, stream>>>(wih);
    k_h1<<<dim3((BB * SS * EE + 255) / 256), dim3(256), 0, stream>>>();
    kg_g2<<<grid64(NPAIR, G4), dim3(256), 0, stream>>>(whh);
    k_h2<<<dim3(NPAIR), dim3(256), 0, stream>>>();

    for (int L = SS; L >= 3; L--) {
        kg_su<<<grid32(BB, NSU), dim3(256), 0, stream>>>(L - 1);
        k_smu<<<dim3(BB), dim3(512), 0, stream>>>(SS - L, 0, L, emb, out);
        kg_Gi<<<grid32(BB, G4), dim3(256), 0, stream>>>(wih);
        kg_g2i<<<grid32(2 * BB, G4), dim3(256), 0, stream>>>(whh);
        k_h2i<<<dim3(2 * BB), dim3(256), 0, stream>>>(L);
    }

    // L == 2: pair 0's h2 is the final x; final k_smu writes scores + loss region
    kg_su<<<grid32(BB, NSU), dim3(256), 0, stream>>>(1);
    k_smu<<<dim3(BB), dim3(512), 0, stream>>>(15, 1, 2, emb, out);

    (void)in_sizes; (void)n_in; (void)out_size; (void)d_ws; (void)ws_size;
}

// Round 14
// 2734.595 us; speedup vs baseline: 1.1290x; 1.1290x over previous
//
#include <hip/hip_runtime.h>
#include <hip/hip_bf16.h>

#define BB 128
#define SS 16
#define EE 512
#define RR 500
#define G4 2048          // 4*E
#define OUT0 64128       // B*501 : scores chunk first
#define NSC 501          // R+1
#define NPAIR 2047       // uniform pair rows m=0..2046 (p==15 junk, never read)
#define NSU 1012         // 500 scores | 512 u

__device__ __forceinline__ float sigm(float x) { return 1.f / (1.f + expf(-x)); }

// ================= device-global pipeline buffers =================
__device__ float g_blstm[G4];
__device__ float g_fcw[EE + 4];          // fc_w, fc_b at [EE]
__device__ float g_qbias[1024];          // fcq_b | fck_b
__device__ float g_Krel[RR * EE];
__device__ float g_cur[BB * SS * EE];    // strided rows m = b*16 + j
__device__ float g_G[BB * SS * G4];      // persistent, shifted incrementally
__device__ float g_h1[BB * SS * EE];
__device__ float g_c1[BB * SS * EE];
__device__ float g_h2[BB * SS * EE];     // pair p at row b*16+p
__device__ float g_g2[BB * SS * G4];     // init scratch; first 256 rows reused per-iter
__device__ float g_sc[BB * SS];
__device__ float g_ent[BB * SS];
__device__ int   g_sel[BB];
// attention precomputes + fused buffers
__device__ float g_fckwT[EE * EE];
__device__ float g_W2[RR * EE];          // W2[k,e] = sum_e' Krel[k,e'] fcq[e',e]
__device__ float g_Mx[EE * EE];          // Mx[f,e] = sum_e' fcq[e',e] fck[e',f]
__device__ float g_c2[RR + 4];           // c2[k] = Krel[k,:]·bq
__device__ float g_v1[EE];               // v1[e] = fck^T bq + fcq^T bk
__device__ float g_c0[1];                // bq·bk
__device__ float g_su[BB * NSU];         // per-iter: scores | u

// ================= setup =================
__global__ void k_prep(const float* __restrict__ bih, const float* __restrict__ bhh,
                       const float* __restrict__ fcwv, const float* __restrict__ fcbv,
                       const float* __restrict__ fcqb, const float* __restrict__ fckb) {
    int i = blockIdx.x * blockDim.x + threadIdx.x;
    if (i < G4) g_blstm[i] = bih[i] + bhh[i];
    if (i < EE) {
        g_fcw[i] = fcwv[i];
        g_qbias[i] = fcqb[i];
        g_qbias[EE + i] = fckb[i];
    }
    if (i == 0) g_fcw[EE] = fcbv[0];
}

__global__ void k_gather(const int* __restrict__ tok, const float* __restrict__ emb) {
    int i = blockIdx.x * blockDim.x + threadIdx.x;
    if (i >= BB * SS * EE) return;
    int e = i & (EE - 1);
    int r = i >> 9;
    int t = tok[r];
    g_cur[i] = emb[(size_t)t * EE + e];
}

__global__ void k_tr(const float* __restrict__ fckw) {
    int i = blockIdx.x * blockDim.x + threadIdx.x;   // 512*512
    if (i >= EE * EE) return;
    int ep = i >> 9;
    int f = i & (EE - 1);
    g_fckwT[(size_t)f * EE + ep] = fckw[(size_t)ep * EE + f];
}

// c2 / v1 / c0 precompute
__global__ __launch_bounds__(512) void k_vprep(const float* __restrict__ fcqw, const float* __restrict__ fckw) {
    __shared__ float sh[512];
    int t = threadIdx.x;
    int blk = blockIdx.x;
    if (blk == 0) {
        float acc = 0.f;
        for (int ep = 0; ep < EE; ep++)
            acc += g_qbias[ep] * fckw[(size_t)ep * EE + t] + g_qbias[EE + ep] * fcqw[(size_t)ep * EE + t];
        g_v1[t] = acc;
    } else if (blk == 1) {
        sh[t] = g_qbias[t] * g_qbias[EE + t];
        __syncthreads();
        for (int s = 256; s > 0; s >>= 1) { if (t < s) sh[t] += sh[t + s]; __syncthreads(); }
        if (t == 0) g_c0[0] = sh[0];
    } else {
        int k = blk - 2;
        sh[t] = g_Krel[(size_t)k * EE + t] * g_qbias[t];
        __syncthreads();
        for (int s = 256; s > 0; s >>= 1) { if (t < s) sh[t] += sh[t + s]; __syncthreads(); }
        if (t == 0) g_c2[k] = sh[0];
    }
}

// ================= fp32 GEMM tile core (32x64, R12-proven) =================
#define TM 32
#define TN 64
#define TK 32
__device__ __forceinline__ void gemm_dev(
    const float* __restrict__ A, int lda,
    const float* __restrict__ W, int ldw, int wtrans,
    const float* __restrict__ bias, const float* __restrict__ Dadd, int ldd,
    float* __restrict__ C, int ldc, int M, int N, int K)
{
    __shared__ float As[TM][TK + 1];
    __shared__ float Ws[TN][TK + 1];
    int tid = threadIdx.x;
    int mt = blockIdx.y * TM;
    int nt = blockIdx.x * TN;
    int tr = tid >> 4;
    int tc = tid & 15;
    float acc[2][4] = {{0.f,0.f,0.f,0.f},{0.f,0.f,0.f,0.f}};

    int ea = tid * 4;
    int ra = ea >> 5;
    int ka = ea & 31;
    int gmA = mt + ra;
    bool rokA = gmA < M;
    int ew = tid * 8;
    int rw = ew >> 5;
    int kw = ew & 31;
    int gnW = nt + rw;
    bool rokW = gnW < N;

    for (int kt = 0; kt < K; kt += TK) {
        #pragma unroll
        for (int i = 0; i < 4; i++) {
            int gk = kt + ka + i;
            float v = 0.f;
            if (rokA && gk < K) v = A[(size_t)gmA * lda + gk];
            As[ra][ka + i] = v;
        }
        #pragma unroll
        for (int i = 0; i < 8; i++) {
            int gk = kt + kw + i;
            float v = 0.f;
            if (rokW && gk < K)
                v = wtrans ? W[(size_t)gk * ldw + gnW] : W[(size_t)gnW * ldw + gk];
            Ws[rw][kw + i] = v;
        }
        __syncthreads();
        #pragma unroll
        for (int kk = 0; kk < TK; kk++) {
            float a0 = As[2 * tr][kk];
            float a1 = As[2 * tr + 1][kk];
            float w0 = Ws[4 * tc + 0][kk];
            float w1 = Ws[4 * tc + 1][kk];
            float w2 = Ws[4 * tc + 2][kk];
            float w3 = Ws[4 * tc + 3][kk];
            acc[0][0] += a0 * w0; acc[0][1] += a0 * w1; acc[0][2] += a0 * w2; acc[0][3] += a0 * w3;
            acc[1][0] += a1 * w0; acc[1][1] += a1 * w1; acc[1][2] += a1 * w2; acc[1][3] += a1 * w3;
        }
        __syncthreads();
    }
    #pragma unroll
    for (int i = 0; i < 2; i++) {
        int gm = mt + 2 * tr + i;
        if (gm >= M) continue;
        #pragma unroll
        for (int j = 0; j < 4; j++) {
            int gn = nt + 4 * tc + j;
            if (gn >= N) continue;
            float v = acc[i][j];
            if (bias) v += bias[gn];
            if (Dadd) v += Dadd[(size_t)gm * ldd + gn];
            C[(size_t)gm * ldc + gn] = v;
        }
    }
}

// ---- full GEMM wrappers ----
__global__ __launch_bounds__(256) void kg_Krel(const float* __restrict__ emb, const float* __restrict__ fckw) {
    gemm_dev(emb, EE, fckw, EE, 0, g_qbias + EE, nullptr, 0, g_Krel, EE, RR, EE, EE);
}
__global__ __launch_bounds__(256) void kg_W2(const float* __restrict__ fcqw) {
    gemm_dev(g_Krel, EE, fcqw, EE, 1, nullptr, nullptr, 0, g_W2, EE, RR, EE, EE);
}
__global__ __launch_bounds__(256) void kg_Mx(const float* __restrict__ fcqw) {
    gemm_dev(g_fckwT, EE, fcqw, EE, 1, nullptr, nullptr, 0, g_Mx, EE, EE, EE, EE);
}
__global__ __launch_bounds__(256) void kg_G(const float* __restrict__ wih) {
    gemm_dev(g_cur, EE, wih, EE, 0, g_blstm, nullptr, 0, g_G, G4, BB * SS, G4, EE);
}
__global__ __launch_bounds__(256) void kg_g2(const float* __restrict__ whh) {
    gemm_dev(g_h1, EE, whh, EE, 0, nullptr, g_G + G4, G4, g_g2, G4, NPAIR, G4, EE);
}

// ---- fused argmax + scores|u GEMM: A row = h2[b*16+sel[b]]; N=1012 ----
__global__ __launch_bounds__(256) void kg_su(int P) {
    __shared__ float As[TM][TK + 1];
    __shared__ float Ws[TN][TK + 1];
    __shared__ int s_sel[TM];
    int tid = threadIdx.x;
    int mt = blockIdx.y * TM;
    int nt = blockIdx.x * TN;
    int tr = tid >> 4;
    int tc = tid & 15;
    float acc[2][4] = {{0.f,0.f,0.f,0.f},{0.f,0.f,0.f,0.f}};

    if (tid < TM) {
        int b = mt + tid;                    // M = BB exact
        float best = -1e30f; int bi = 0;
        for (int p = 0; p < P; p++) {
            float v = g_sc[b * SS + p];
            if (v > best) { best = v; bi = p; }
        }
        s_sel[tid] = bi;
        if (blockIdx.x == 0) g_sel[b] = bi;
    }
    __syncthreads();

    int ea = tid * 4;
    int ra = ea >> 5;
    int ka = ea & 31;
    int gmA = mt + ra;
    int physA = gmA * SS + s_sel[ra];
    int ew = tid * 8;
    int rw = ew >> 5;
    int kw = ew & 31;
    int gnW = nt + rw;
    bool rokW = gnW < NSU;
    const float* Wrow = nullptr;
    if (rokW) Wrow = (gnW < RR) ? (g_W2 + (size_t)gnW * EE) : (g_Mx + (size_t)(gnW - RR) * EE);

    for (int kt = 0; kt < EE; kt += TK) {
        #pragma unroll
        for (int i = 0; i < 4; i++)
            As[ra][ka + i] = g_h2[(size_t)physA * EE + kt + ka + i];
        #pragma unroll
        for (int i = 0; i < 8; i++)
            Ws[rw][kw + i] = rokW ? Wrow[kt + kw + i] : 0.f;
        __syncthreads();
        #pragma unroll
        for (int kk = 0; kk < TK; kk++) {
            float a0 = As[2 * tr][kk];
            float a1 = As[2 * tr + 1][kk];
            float w0 = Ws[4 * tc + 0][kk];
            float w1 = Ws[4 * tc + 1][kk];
            float w2 = Ws[4 * tc + 2][kk];
            float w3 = Ws[4 * tc + 3][kk];
            acc[0][0] += a0 * w0; acc[0][1] += a0 * w1; acc[0][2] += a0 * w2; acc[0][3] += a0 * w3;
            acc[1][0] += a1 * w0; acc[1][1] += a1 * w1; acc[1][2] += a1 * w2; acc[1][3] += a1 * w3;
        }
        __syncthreads();
    }
    #pragma unroll
    for (int i = 0; i < 2; i++) {
        int gm = mt + 2 * tr + i;
        #pragma unroll
        for (int j = 0; j < 4; j++) {
            int gn = nt + 4 * tc + j;
            if (gn >= NSU) continue;
            g_su[(size_t)gm * NSU + gn] = acc[i][j] + (gn < RR ? g_c2[gn] : 0.f);
        }
    }
}

// ---- fused incremental G + h1 + c1: gate-major tiling ----
// M=BB rows (phys = b*16+sel); N = 512 e-cols x 4 gates; epilogue does the cell math once.
#define GNE 32
__global__ __launch_bounds__(256) void kg_Gih1(const float* __restrict__ wih) {
    __shared__ float As[TM][TK + 1];
    __shared__ float Ws[4][GNE][TK + 1];
    __shared__ int s_sel[TM];
    int tid = threadIdx.x;
    int mt = blockIdx.y * TM;       // batch tile (4 blocks)
    int nt = blockIdx.x * GNE;      // e-col tile (16 blocks)
    int tr = tid >> 4;              // 0..15
    int tc = tid & 15;              // 0..15
    float acc[2][2][4];             // [row][e][gate]
    #pragma unroll
    for (int i = 0; i < 2; i++)
        #pragma unroll
        for (int j = 0; j < 2; j++)
            #pragma unroll
            for (int q = 0; q < 4; q++) acc[i][j][q] = 0.f;

    if (tid < TM) s_sel[tid] = g_sel[mt + tid];
    __syncthreads();

    int ea = tid * 4;               // A: 32x32 = 1024 / 256 thr
    int ra = ea >> 5;
    int ka = ea & 31;
    int physA = (mt + ra) * SS + s_sel[ra];
    // W: 4 gates x 32 n x 32 k = 4096 / 256 thr = 16/thread: thread handles one (gate,n) row pair
    int ewq = tid >> 6;             // gate 0..3
    int ewn = (tid >> 2) & 15;      // 16 of 32 n-rows -> 2 rows per thread
    int ewk = (tid & 3) * 8;        // 8 k per chunk

    for (int kt = 0; kt < EE; kt += TK) {
        #pragma unroll
        for (int i = 0; i < 4; i++)
            As[ra][ka + i] = g_cur[(size_t)physA * EE + kt + ka + i];
        #pragma unroll
        for (int rr = 0; rr < 2; rr++) {
            int n = 2 * ewn + rr;
            const float* wrow = wih + (size_t)(ewq * EE + nt + n) * EE + kt;
            #pragma unroll
            for (int i = 0; i < 8; i++)
                Ws[ewq][n][ewk + i] = wrow[ewk + i];
        }
        __syncthreads();
        #pragma unroll
        for (int kk = 0; kk < TK; kk++) {
            float a0 = As[2 * tr][kk];
            float a1 = As[2 * tr + 1][kk];
            #pragma unroll
            for (int q = 0; q < 4; q++) {
                float w0 = Ws[q][2 * tc][kk];
                float w1 = Ws[q][2 * tc + 1][kk];
                acc[0][0][q] += a0 * w0; acc[0][1][q] += a0 * w1;
                acc[1][0][q] += a1 * w0; acc[1][1][q] += a1 * w1;
            }
        }
        __syncthreads();
    }
    #pragma unroll
    for (int i = 0; i < 2; i++) {
        int gm = mt + 2 * tr + i;
        int phys = gm * SS + s_sel[2 * tr + i];
        #pragma unroll
        for (int j = 0; j < 2; j++) {
            int e = nt + 2 * tc + j;
            float gi = acc[i][j][0] + g_blstm[e];
            float gf = acc[i][j][1] + g_blstm[512 + e];
            float gg = acc[i][j][2] + g_blstm[1024 + e];
            float go = acc[i][j][3] + g_blstm[1536 + e];
            size_t grow = (size_t)phys * G4;
            g_G[grow + e] = gi;
            g_G[grow + 512 + e] = gf;
            g_G[grow + 1024 + e] = gg;
            g_G[grow + 1536 + e] = go;
            float c = sigm(gi) * tanhf(gg);
            g_c1[(size_t)phys * EE + e] = c;
            g_h1[(size_t)phys * EE + e] = sigm(go) * tanhf(c);
        }
    }
}

// ---- incremental GEMM: g2 for 2 pairs/batch; M=2*BB (R12-proven) ----
__global__ __launch_bounds__(256) void kg_g2i(const float* __restrict__ whh) {
    __shared__ float As[TM][TK + 1];
    __shared__ float Ws[TN][TK + 1];
    int tid = threadIdx.x;
    int mt = blockIdx.y * TM;
    int nt = blockIdx.x * TN;
    int tr = tid >> 4;
    int tc = tid & 15;
    float acc[2][4] = {{0.f,0.f,0.f,0.f},{0.f,0.f,0.f,0.f}};

    int ea = tid * 4;
    int ra = ea >> 5;
    int ka = ea & 31;
    int gmA = mt + ra;
    int bA = gmA >> 1;
    int pA = g_sel[bA] - 1 + (gmA & 1);
    pA = min(max(pA, 0), 14);
    int physA = bA * SS + pA;
    int ew = tid * 8;
    int rw = ew >> 5;
    int kw = ew & 31;
    int gnW = nt + rw;

    for (int kt = 0; kt < EE; kt += TK) {
        #pragma unroll
        for (int i = 0; i < 4; i++)
            As[ra][ka + i] = g_h1[(size_t)physA * EE + kt + ka + i];
        #pragma unroll
        for (int i = 0; i < 8; i++)
            Ws[rw][kw + i] = whh[(size_t)gnW * EE + kt + kw + i];
        __syncthreads();
        #pragma unroll
        for (int kk = 0; kk < TK; kk++) {
            float a0 = As[2 * tr][kk];
            float a1 = As[2 * tr + 1][kk];
            float w0 = Ws[4 * tc + 0][kk];
            float w1 = Ws[4 * tc + 1][kk];
            float w2 = Ws[4 * tc + 2][kk];
            float w3 = Ws[4 * tc + 3][kk];
            acc[0][0] += a0 * w0; acc[0][1] += a0 * w1; acc[0][2] += a0 * w2; acc[0][3] += a0 * w3;
            acc[1][0] += a1 * w0; acc[1][1] += a1 * w1; acc[1][2] += a1 * w2; acc[1][3] += a1 * w3;
        }
        __syncthreads();
    }
    #pragma unroll
    for (int i = 0; i < 2; i++) {
        int gm = mt + 2 * tr + i;
        int b = gm >> 1;
        int p = min(max(g_sel[b] - 1 + (gm & 1), 0), 14);
        size_t drow = (size_t)(b * SS + p + 1) * G4;
        #pragma unroll
        for (int j = 0; j < 4; j++) {
            int gn = nt + 4 * tc + j;
            g_g2[(size_t)gm * G4 + gn] = acc[i][j] + g_G[drow + gn];
        }
    }
}

// ================= LSTM elementwise (init) =================
__global__ void k_h1() {
    int idx = blockIdx.x * blockDim.x + threadIdx.x;
    if (idx >= BB * SS * EE) return;
    int m = idx >> 9;
    int e = idx & (EE - 1);
    const float* g = g_G + (size_t)m * G4;
    float c = sigm(g[e]) * tanhf(g[1024 + e]);
    g_c1[idx] = c;
    g_h1[idx] = sigm(g[1536 + e]) * tanhf(c);
}

__global__ __launch_bounds__(256) void k_h2() {
    int m = blockIdx.x;                 // 0..2046
    const float* g = g_g2 + (size_t)m * G4;
    __shared__ float red[256];
    float part = 0.f;
    for (int e = threadIdx.x; e < EE; e += 256) {
        float c = sigm(g[512 + e]) * g_c1[(size_t)m * EE + e] + sigm(g[e]) * tanhf(g[1024 + e]);
        float h = sigm(g[1536 + e]) * tanhf(c);
        g_h2[(size_t)m * EE + e] = h;
        part += h * g_fcw[e];
    }
    red[threadIdx.x] = part;
    __syncthreads();
    for (int s = 128; s > 0; s >>= 1) {
        if (threadIdx.x < s) red[threadIdx.x] += red[threadIdx.x + s];
        __syncthreads();
    }
    if (threadIdx.x == 0) g_sc[m] = sigm(red[0] + g_fcw[EE]);
}

// per-iter h2/sc for the 2 candidate pairs
__global__ __launch_bounds__(256) void k_h2i(int L) {
    int m = blockIdx.x;                 // 0..255
    int b = m >> 1;
    int t = m & 1;
    int s = g_sel[b];
    int p = s - 1 + t;
    bool valid = t == 0 ? (s >= 1) : (s <= L - 3);
    if (!valid) return;
    const float* g = g_g2 + (size_t)m * G4;
    int cr = b * SS + p;
    __shared__ float red[256];
    float part = 0.f;
    for (int e = threadIdx.x; e < EE; e += 256) {
        float c = sigm(g[512 + e]) * g_c1[(size_t)cr * EE + e] + sigm(g[e]) * tanhf(g[1024 + e]);
        float h = sigm(g[1536 + e]) * tanhf(c);
        g_h2[(size_t)cr * EE + e] = h;
        part += h * g_fcw[e];
    }
    red[threadIdx.x] = part;
    __syncthreads();
    for (int ss = 128; ss > 0; ss >>= 1) {
        if (threadIdx.x < ss) red[threadIdx.x] += red[threadIdx.x + ss];
        __syncthreads();
    }
    if (threadIdx.x == 0) g_sc[cr] = sigm(red[0] + g_fcw[EE]);
}

// ================= fused softmax + entropy + merged + shift (+final output) =================
__global__ __launch_bounds__(512) void k_smu(int col, int finalFlag, int L,
                                             const float* __restrict__ emb, float* __restrict__ out) {
    int b = blockIdx.x;
    int t = threadIdx.x;      // 0..511
    __shared__ float sh[512];
    __shared__ float srow[NSC];
    __shared__ float s_p500;
    const float* su = g_su + (size_t)b * NSU;
    int s = g_sel[b];
    const float* h2row = g_h2 + (size_t)(b * SS + s) * EE;
    const float isq = 0.044194173824159216f;   // 1/sqrt(512)

    float hv = h2row[t];
    sh[t] = hv * (su[RR + t] + g_v1[t]);
    __syncthreads();
    for (int ss = 256; ss > 0; ss >>= 1) { if (t < ss) sh[t] += sh[t + ss]; __syncthreads(); }
    if (t == 0) srow[RR] = (sh[0] + g_c0[0]) * isq;
    __syncthreads();
    if (t < RR) srow[t] = su[t] * isq;
    __syncthreads();
    float mx = (t < NSC) ? srow[t] : -1e30f;
    sh[t] = mx; __syncthreads();
    for (int ss = 256; ss > 0; ss >>= 1) { if (t < ss) sh[t] = fmaxf(sh[t], sh[t + ss]); __syncthreads(); }
    mx = sh[0]; __syncthreads();
    float zp = (t < NSC) ? expf(srow[t] - mx) : 0.f;
    sh[t] = zp; __syncthreads();
    for (int ss = 256; ss > 0; ss >>= 1) { if (t < ss) sh[t] += sh[t + ss]; __syncthreads(); }
    float lse = mx + logf(sh[0]);
    __syncthreads();
    float p = (t < NSC) ? expf(srow[t] - lse) : 0.f;
    float ep = (t < NSC) ? p * (lse - srow[t]) : 0.f;
    if (finalFlag && t < NSC) out[(size_t)b * NSC + t] = srow[t];
    sh[t] = ep; __syncthreads();
    for (int ss = 256; ss > 0; ss >>= 1) { if (t < ss) sh[t] += sh[t + ss]; __syncthreads(); }
    if (finalFlag) {
        if (t < 16) {
            float v = (t == 15) ? sh[0] : ((t == 14) ? 0.f : g_ent[b * SS + t]);
            out[OUT0 + b * 16 + t] = v;
        }
        return;
    }
    if (t == 0) g_ent[b * SS + col] = sh[0];

    __syncthreads();
    if (t < NSC) srow[t] = p;            // prob in place
    if (t == RR) s_p500 = p;
    __syncthreads();
    float macc = 0.f;
    #pragma unroll 4
    for (int k = 0; k < RR; k++) macc += srow[k] * emb[(size_t)k * EE + t];
    float newv = macc + s_p500 * hv;
    size_t base = (size_t)b * SS * EE;
    size_t gbase = (size_t)b * SS * G4;
    for (int j = s + 1; j <= L - 2; j++) {
        g_cur[base + (size_t)j * EE + t] = g_cur[base + (size_t)(j + 1) * EE + t];
        g_h1 [base + (size_t)j * EE + t] = g_h1 [base + (size_t)(j + 1) * EE + t];
        g_c1 [base + (size_t)j * EE + t] = g_c1 [base + (size_t)(j + 1) * EE + t];
        #pragma unroll
        for (int q = 0; q < 4; q++)
            g_G[gbase + (size_t)j * G4 + t + q * 512] = g_G[gbase + (size_t)(j + 1) * G4 + t + q * 512];
    }
    g_cur[base + (size_t)s * EE + t] = newv;
    for (int pp = s + 1; pp <= L - 3; pp++)
        g_h2[base + (size_t)pp * EE + t] = g_h2[base + (size_t)(pp + 1) * EE + t];
    if (t == 0)
        for (int pp = s + 1; pp <= L - 3; pp++) g_sc[b * SS + pp] = g_sc[b * SS + pp + 1];
}

// ================= host launch =================
extern "C" void kernel_launch(void* const* d_in, const int* in_sizes, int n_in,
                              void* d_out, int out_size, void* d_ws, size_t ws_size,
                              hipStream_t stream) {
    const int*   tokens = (const int*)d_in[0];
    const float* emb    = (const float*)d_in[1];
    const float* wih    = (const float*)d_in[2];
    const float* whh    = (const float*)d_in[3];
    const float* bih    = (const float*)d_in[4];
    const float* bhh    = (const float*)d_in[5];
    const float* fcwv   = (const float*)d_in[6];
    const float* fcbv   = (const float*)d_in[7];
    const float* fcqw   = (const float*)d_in[8];
    const float* fcqb   = (const float*)d_in[9];
    const float* fckw   = (const float*)d_in[10];
    const float* fckb   = (const float*)d_in[11];
    float* out = (float*)d_out;

    auto grid32 = [](int M, int N) { return dim3((unsigned)((N + TN - 1) / TN), (unsigned)((M + TM - 1) / TM)); };

    // ---- setup + attention precomputes (once) ----
    k_prep<<<dim3(8), dim3(256), 0, stream>>>(bih, bhh, fcwv, fcbv, fcqb, fckb);
    kg_Krel<<<grid32(RR, EE), dim3(256), 0, stream>>>(emb, fckw);
    k_tr<<<dim3((EE * EE + 255) / 256), dim3(256), 0, stream>>>(fckw);
    kg_W2<<<grid32(RR, EE), dim3(256), 0, stream>>>(fcqw);
    kg_Mx<<<grid32(EE, EE), dim3(256), 0, stream>>>(fcqw);
    k_vprep<<<dim3(502), dim3(512), 0, stream>>>(fcqw, fckw);
    k_gather<<<dim3((BB * SS * EE + 255) / 256), dim3(256), 0, stream>>>(tokens, emb);

    // ---- initial full LSTM pass (once) ----
    kg_G<<<grid32(BB * SS, G4), dim3(256), 0, stream>>>(wih);
    k_h1<<<dim3((BB * SS * EE + 255) / 256), dim3(256), 0, stream>>>();
    kg_g2<<<grid32(NPAIR, G4), dim3(256), 0, stream>>>(whh);
    k_h2<<<dim3(NPAIR), dim3(256), 0, stream>>>();

    for (int L = SS; L >= 3; L--) {
        kg_su<<<grid32(BB, NSU), dim3(256), 0, stream>>>(L - 1);
        k_smu<<<dim3(BB), dim3(512), 0, stream>>>(SS - L, 0, L, emb, out);
        kg_Gih1<<<dim3(EE / GNE, BB / TM), dim3(256), 0, stream>>>(wih);
        kg_g2i<<<grid32(2 * BB, G4), dim3(256), 0, stream>>>(whh);
        k_h2i<<<dim3(2 * BB), dim3(256), 0, stream>>>(L);
    }

    // L == 2: pair 0's h2 is the final x; final k_smu writes scores + loss region
    kg_su<<<grid32(BB, NSU), dim3(256), 0, stream>>>(1);
    k_smu<<<dim3(BB), dim3(512), 0, stream>>>(15, 1, 2, emb, out);

    (void)in_sizes; (void)n_in; (void)out_size; (void)d_ws; (void)ws_size;
}

// Round 15
// 2504.666 us; speedup vs baseline: 1.2326x; 1.0918x over previous
//
#include <hip/hip_runtime.h>
#include <hip/hip_bf16.h>

#define BB 128
#define SS 16
#define EE 512
#define RR 500
#define G4 2048          // 4*E
#define OUT0 64128       // B*501 : scores chunk first
#define NSC 501          // R+1
#define NPAIR 2047       // init pair rows m=0..2046 (p==15 junk, never read)
#define NSU 1012         // 500 scores | 512 u

__device__ __forceinline__ float sigm(float x) { return 1.f / (1.f + expf(-x)); }

// ================= device-global pipeline buffers =================
__device__ float g_blstm[G4];
__device__ float g_fcw[EE + 4];          // fc_w, fc_b at [EE]
__device__ float g_qbias[1024];          // fcq_b | fck_b
__device__ float g_Krel[RR * EE];
__device__ float g_cur[BB * SS * EE];    // physical rows, never shifted
__device__ float g_G[BB * SS * G4];
__device__ float g_h1[BB * SS * EE];
__device__ float g_c1[BB * SS * EE];
__device__ float g_h2[BB * SS * EE];     // pair keyed by physical row of left elem
__device__ float g_g2[BB * SS * G4];     // init scratch; first 256 rows reused per-iter
__device__ float g_sc[BB * SS];          // LOGICAL pair index (shifted, tiny)
__device__ float g_ent[BB * SS];
__device__ int   g_sel[BB];
__device__ int   g_ord[BB * SS];         // logical pos -> physical row (within batch: b*16+?)
// attention precomputes + fused buffers
__device__ float g_fckwT[EE * EE];
__device__ float g_W2[RR * EE];          // W2[k,e] = sum_e' Krel[k,e'] fcq[e',e]
__device__ float g_Mx[EE * EE];          // Mx[f,e] = sum_e' fcq[e',e] fck[e',f]
__device__ float g_c2[RR + 4];           // c2[k] = Krel[k,:]·bq
__device__ float g_v1[EE];               // v1[e] = fck^T bq + fcq^T bk
__device__ float g_c0[1];                // bq·bk
__device__ float g_su[BB * NSU];         // per-iter: scores | u

// ================= setup =================
__global__ void k_prep(const float* __restrict__ bih, const float* __restrict__ bhh,
                       const float* __restrict__ fcwv, const float* __restrict__ fcbv,
                       const float* __restrict__ fcqb, const float* __restrict__ fckb) {
    int i = blockIdx.x * blockDim.x + threadIdx.x;   // 2048
    if (i < G4) g_blstm[i] = bih[i] + bhh[i];
    if (i < EE) {
        g_fcw[i] = fcwv[i];
        g_qbias[i] = fcqb[i];
        g_qbias[EE + i] = fckb[i];
    }
    if (i == 0) g_fcw[EE] = fcbv[0];
    if (i < BB * SS) g_ord[i] = i;       // identity permutation
}

__global__ void k_gather(const int* __restrict__ tok, const float* __restrict__ emb) {
    int i = blockIdx.x * blockDim.x + threadIdx.x;
    if (i >= BB * SS * EE) return;
    int e = i & (EE - 1);
    int r = i >> 9;
    int t = tok[r];
    g_cur[i] = emb[(size_t)t * EE + e];
}

__global__ void k_tr(const float* __restrict__ fckw) {
    int i = blockIdx.x * blockDim.x + threadIdx.x;   // 512*512
    if (i >= EE * EE) return;
    int ep = i >> 9;
    int f = i & (EE - 1);
    g_fckwT[(size_t)f * EE + ep] = fckw[(size_t)ep * EE + f];
}

__global__ __launch_bounds__(512) void k_vprep(const float* __restrict__ fcqw, const float* __restrict__ fckw) {
    __shared__ float sh[512];
    int t = threadIdx.x;
    int blk = blockIdx.x;
    if (blk == 0) {
        float acc = 0.f;
        for (int ep = 0; ep < EE; ep++)
            acc += g_qbias[ep] * fckw[(size_t)ep * EE + t] + g_qbias[EE + ep] * fcqw[(size_t)ep * EE + t];
        g_v1[t] = acc;
    } else if (blk == 1) {
        sh[t] = g_qbias[t] * g_qbias[EE + t];
        __syncthreads();
        for (int s = 256; s > 0; s >>= 1) { if (t < s) sh[t] += sh[t + s]; __syncthreads(); }
        if (t == 0) g_c0[0] = sh[0];
    } else {
        int k = blk - 2;
        sh[t] = g_Krel[(size_t)k * EE + t] * g_qbias[t];
        __syncthreads();
        for (int s = 256; s > 0; s >>= 1) { if (t < s) sh[t] += sh[t + s]; __syncthreads(); }
        if (t == 0) g_c2[k] = sh[0];
    }
}

// ================= fp32 GEMM tile core (32x64, proven) =================
#define TM 32
#define TN 64
#define TK 32
__device__ __forceinline__ void gemm_dev(
    const float* __restrict__ A, int lda,
    const float* __restrict__ W, int ldw, int wtrans,
    const float* __restrict__ bias, const float* __restrict__ Dadd, int ldd,
    float* __restrict__ C, int ldc, int M, int N, int K)
{
    __shared__ float As[TM][TK + 1];
    __shared__ float Ws[TN][TK + 1];
    int tid = threadIdx.x;
    int mt = blockIdx.y * TM;
    int nt = blockIdx.x * TN;
    int tr = tid >> 4;
    int tc = tid & 15;
    float acc[2][4] = {{0.f,0.f,0.f,0.f},{0.f,0.f,0.f,0.f}};

    int ea = tid * 4;
    int ra = ea >> 5;
    int ka = ea & 31;
    int gmA = mt + ra;
    bool rokA = gmA < M;
    int ew = tid * 8;
    int rw = ew >> 5;
    int kw = ew & 31;
    int gnW = nt + rw;
    bool rokW = gnW < N;

    for (int kt = 0; kt < K; kt += TK) {
        #pragma unroll
        for (int i = 0; i < 4; i++) {
            int gk = kt + ka + i;
            float v = 0.f;
            if (rokA && gk < K) v = A[(size_t)gmA * lda + gk];
            As[ra][ka + i] = v;
        }
        #pragma unroll
        for (int i = 0; i < 8; i++) {
            int gk = kt + kw + i;
            float v = 0.f;
            if (rokW && gk < K)
                v = wtrans ? W[(size_t)gk * ldw + gnW] : W[(size_t)gnW * ldw + gk];
            Ws[rw][kw + i] = v;
        }
        __syncthreads();
        #pragma unroll
        for (int kk = 0; kk < TK; kk++) {
            float a0 = As[2 * tr][kk];
            float a1 = As[2 * tr + 1][kk];
            float w0 = Ws[4 * tc + 0][kk];
            float w1 = Ws[4 * tc + 1][kk];
            float w2 = Ws[4 * tc + 2][kk];
            float w3 = Ws[4 * tc + 3][kk];
            acc[0][0] += a0 * w0; acc[0][1] += a0 * w1; acc[0][2] += a0 * w2; acc[0][3] += a0 * w3;
            acc[1][0] += a1 * w0; acc[1][1] += a1 * w1; acc[1][2] += a1 * w2; acc[1][3] += a1 * w3;
        }
        __syncthreads();
    }
    #pragma unroll
    for (int i = 0; i < 2; i++) {
        int gm = mt + 2 * tr + i;
        if (gm >= M) continue;
        #pragma unroll
        for (int j = 0; j < 4; j++) {
            int gn = nt + 4 * tc + j;
            if (gn >= N) continue;
            float v = acc[i][j];
            if (bias) v += bias[gn];
            if (Dadd) v += Dadd[(size_t)gm * ldd + gn];
            C[(size_t)gm * ldc + gn] = v;
        }
    }
}

// ---- full GEMM wrappers ----
__global__ __launch_bounds__(256) void kg_Krel(const float* __restrict__ emb, const float* __restrict__ fckw) {
    gemm_dev(emb, EE, fckw, EE, 0, g_qbias + EE, nullptr, 0, g_Krel, EE, RR, EE, EE);
}
__global__ __launch_bounds__(256) void kg_W2(const float* __restrict__ fcqw) {
    gemm_dev(g_Krel, EE, fcqw, EE, 1, nullptr, nullptr, 0, g_W2, EE, RR, EE, EE);
}
__global__ __launch_bounds__(256) void kg_Mx(const float* __restrict__ fcqw) {
    gemm_dev(g_fckwT, EE, fcqw, EE, 1, nullptr, nullptr, 0, g_Mx, EE, EE, EE, EE);
}
__global__ __launch_bounds__(256) void kg_G(const float* __restrict__ wih) {
    gemm_dev(g_cur, EE, wih, EE, 0, g_blstm, nullptr, 0, g_G, G4, BB * SS, G4, EE);
}
__global__ __launch_bounds__(256) void kg_g2(const float* __restrict__ whh) {
    gemm_dev(g_h1, EE, whh, EE, 0, nullptr, g_G + G4, G4, g_g2, G4, NPAIR, G4, EE);
}

// ---- fused argmax + scores|u GEMM: A row = h2[ord[sel]]; N=1012 ----
__global__ __launch_bounds__(256) void kg_su(int P) {
    __shared__ float As[TM][TK + 1];
    __shared__ float Ws[TN][TK + 1];
    __shared__ int s_phys[TM];
    int tid = threadIdx.x;
    int mt = blockIdx.y * TM;
    int nt = blockIdx.x * TN;
    int tr = tid >> 4;
    int tc = tid & 15;
    float acc[2][4] = {{0.f,0.f,0.f,0.f},{0.f,0.f,0.f,0.f}};

    if (tid < TM) {
        int b = mt + tid;                    // M = BB exact
        float best = -1e30f; int bi = 0;
        for (int p = 0; p < P; p++) {
            float v = g_sc[b * SS + p];
            if (v > best) { best = v; bi = p; }
        }
        s_phys[tid] = g_ord[b * SS + bi];
        if (blockIdx.x == 0) g_sel[b] = bi;
    }
    __syncthreads();

    int ea = tid * 4;
    int ra = ea >> 5;
    int ka = ea & 31;
    int physA = s_phys[ra];
    int ew = tid * 8;
    int rw = ew >> 5;
    int kw = ew & 31;
    int gnW = nt + rw;
    bool rokW = gnW < NSU;
    const float* Wrow = nullptr;
    if (rokW) Wrow = (gnW < RR) ? (g_W2 + (size_t)gnW * EE) : (g_Mx + (size_t)(gnW - RR) * EE);

    for (int kt = 0; kt < EE; kt += TK) {
        #pragma unroll
        for (int i = 0; i < 4; i++)
            As[ra][ka + i] = g_h2[(size_t)physA * EE + kt + ka + i];
        #pragma unroll
        for (int i = 0; i < 8; i++)
            Ws[rw][kw + i] = rokW ? Wrow[kt + kw + i] : 0.f;
        __syncthreads();
        #pragma unroll
        for (int kk = 0; kk < TK; kk++) {
            float a0 = As[2 * tr][kk];
            float a1 = As[2 * tr + 1][kk];
            float w0 = Ws[4 * tc + 0][kk];
            float w1 = Ws[4 * tc + 1][kk];
            float w2 = Ws[4 * tc + 2][kk];
            float w3 = Ws[4 * tc + 3][kk];
            acc[0][0] += a0 * w0; acc[0][1] += a0 * w1; acc[0][2] += a0 * w2; acc[0][3] += a0 * w3;
            acc[1][0] += a1 * w0; acc[1][1] += a1 * w1; acc[1][2] += a1 * w2; acc[1][3] += a1 * w3;
        }
        __syncthreads();
    }
    #pragma unroll
    for (int i = 0; i < 2; i++) {
        int gm = mt + 2 * tr + i;
        #pragma unroll
        for (int j = 0; j < 4; j++) {
            int gn = nt + 4 * tc + j;
            if (gn >= NSU) continue;
            g_su[(size_t)gm * NSU + gn] = acc[i][j] + (gn < RR ? g_c2[gn] : 0.f);
        }
    }
}

// ---- incremental GEMM: G[ord[sel]] = cur[ord[sel]] @ wih^T + b; M=BB ----
__global__ __launch_bounds__(256) void kg_Gi(const float* __restrict__ wih) {
    __shared__ float As[TM][TK + 1];
    __shared__ float Ws[TN][TK + 1];
    __shared__ int s_phys[TM];
    int tid = threadIdx.x;
    int mt = blockIdx.y * TM;
    int nt = blockIdx.x * TN;
    int tr = tid >> 4;
    int tc = tid & 15;
    float acc[2][4] = {{0.f,0.f,0.f,0.f},{0.f,0.f,0.f,0.f}};

    if (tid < TM) {
        int b = mt + tid;
        s_phys[tid] = g_ord[b * SS + g_sel[b]];
    }
    __syncthreads();

    int ea = tid * 4;
    int ra = ea >> 5;
    int ka = ea & 31;
    int physA = s_phys[ra];
    int ew = tid * 8;
    int rw = ew >> 5;
    int kw = ew & 31;
    int gnW = nt + rw;

    for (int kt = 0; kt < EE; kt += TK) {
        #pragma unroll
        for (int i = 0; i < 4; i++)
            As[ra][ka + i] = g_cur[(size_t)physA * EE + kt + ka + i];
        #pragma unroll
        for (int i = 0; i < 8; i++)
            Ws[rw][kw + i] = wih[(size_t)gnW * EE + kt + kw + i];
        __syncthreads();
        #pragma unroll
        for (int kk = 0; kk < TK; kk++) {
            float a0 = As[2 * tr][kk];
            float a1 = As[2 * tr + 1][kk];
            float w0 = Ws[4 * tc + 0][kk];
            float w1 = Ws[4 * tc + 1][kk];
            float w2 = Ws[4 * tc + 2][kk];
            float w3 = Ws[4 * tc + 3][kk];
            acc[0][0] += a0 * w0; acc[0][1] += a0 * w1; acc[0][2] += a0 * w2; acc[0][3] += a0 * w3;
            acc[1][0] += a1 * w0; acc[1][1] += a1 * w1; acc[1][2] += a1 * w2; acc[1][3] += a1 * w3;
        }
        __syncthreads();
    }
    #pragma unroll
    for (int i = 0; i < 2; i++) {
        int phys = s_phys[2 * tr + i];
        #pragma unroll
        for (int j = 0; j < 4; j++) {
            int gn = nt + 4 * tc + j;
            g_G[(size_t)phys * G4 + gn] = acc[i][j] + g_blstm[gn];
        }
    }
}

// ---- incremental h1/c1 for the merged row ----
__global__ void k_h1i() {
    int idx = blockIdx.x * blockDim.x + threadIdx.x;   // BB*EE
    if (idx >= BB * EE) return;
    int b = idx >> 9;
    int e = idx & (EE - 1);
    int phys = g_ord[b * SS + g_sel[b]];
    const float* g = g_G + (size_t)phys * G4;
    float c = sigm(g[e]) * tanhf(g[1024 + e]);
    g_c1[(size_t)phys * EE + e] = c;
    g_h1[(size_t)phys * EE + e] = sigm(g[1536 + e]) * tanhf(c);
}

// ---- incremental GEMM: g2 for 2 candidate pairs/batch; M=2*BB ----
__global__ __launch_bounds__(256) void kg_g2i(const float* __restrict__ whh) {
    __shared__ float As[TM][TK + 1];
    __shared__ float Ws[TN][TK + 1];
    __shared__ int s_physA[TM];
    __shared__ int s_physD[TM];
    int tid = threadIdx.x;
    int mt = blockIdx.y * TM;
    int nt = blockIdx.x * TN;
    int tr = tid >> 4;
    int tc = tid & 15;
    float acc[2][4] = {{0.f,0.f,0.f,0.f},{0.f,0.f,0.f,0.f}};

    if (tid < TM) {
        int gm = mt + tid;
        int b = gm >> 1;
        int p = min(max(g_sel[b] - 1 + (gm & 1), 0), 14);
        s_physA[tid] = g_ord[b * SS + p];        // left elem row (A from h1)
        s_physD[tid] = g_ord[b * SS + p + 1];    // right elem row (D from G)
    }
    __syncthreads();

    int ea = tid * 4;
    int ra = ea >> 5;
    int ka = ea & 31;
    int physA = s_physA[ra];
    int ew = tid * 8;
    int rw = ew >> 5;
    int kw = ew & 31;
    int gnW = nt + rw;

    for (int kt = 0; kt < EE; kt += TK) {
        #pragma unroll
        for (int i = 0; i < 4; i++)
            As[ra][ka + i] = g_h1[(size_t)physA * EE + kt + ka + i];
        #pragma unroll
        for (int i = 0; i < 8; i++)
            Ws[rw][kw + i] = whh[(size_t)gnW * EE + kt + kw + i];
        __syncthreads();
        #pragma unroll
        for (int kk = 0; kk < TK; kk++) {
            float a0 = As[2 * tr][kk];
            float a1 = As[2 * tr + 1][kk];
            float w0 = Ws[4 * tc + 0][kk];
            float w1 = Ws[4 * tc + 1][kk];
            float w2 = Ws[4 * tc + 2][kk];
            float w3 = Ws[4 * tc + 3][kk];
            acc[0][0] += a0 * w0; acc[0][1] += a0 * w1; acc[0][2] += a0 * w2; acc[0][3] += a0 * w3;
            acc[1][0] += a1 * w0; acc[1][1] += a1 * w1; acc[1][2] += a1 * w2; acc[1][3] += a1 * w3;
        }
        __syncthreads();
    }
    #pragma unroll
    for (int i = 0; i < 2; i++) {
        int gm = mt + 2 * tr + i;
        size_t drow = (size_t)s_physD[2 * tr + i] * G4;
        #pragma unroll
        for (int j = 0; j < 4; j++) {
            int gn = nt + 4 * tc + j;
            g_g2[(size_t)gm * G4 + gn] = acc[i][j] + g_G[drow + gn];
        }
    }
}

// ================= LSTM elementwise (init) =================
__global__ void k_h1() {
    int idx = blockIdx.x * blockDim.x + threadIdx.x;
    if (idx >= BB * SS * EE) return;
    int m = idx >> 9;
    int e = idx & (EE - 1);
    const float* g = g_G + (size_t)m * G4;
    float c = sigm(g[e]) * tanhf(g[1024 + e]);
    g_c1[idx] = c;
    g_h1[idx] = sigm(g[1536 + e]) * tanhf(c);
}

__global__ __launch_bounds__(256) void k_h2() {
    int m = blockIdx.x;                 // 0..2046 (identity order at init)
    const float* g = g_g2 + (size_t)m * G4;
    __shared__ float red[256];
    float part = 0.f;
    for (int e = threadIdx.x; e < EE; e += 256) {
        float c = sigm(g[512 + e]) * g_c1[(size_t)m * EE + e] + sigm(g[e]) * tanhf(g[1024 + e]);
        float h = sigm(g[1536 + e]) * tanhf(c);
        g_h2[(size_t)m * EE + e] = h;
        part += h * g_fcw[e];
    }
    red[threadIdx.x] = part;
    __syncthreads();
    for (int s = 128; s > 0; s >>= 1) {
        if (threadIdx.x < s) red[threadIdx.x] += red[threadIdx.x + s];
        __syncthreads();
    }
    if (threadIdx.x == 0) g_sc[m] = sigm(red[0] + g_fcw[EE]);
}

// per-iter h2/sc for the 2 candidate pairs; h2 keyed by physical left row, sc logical
__global__ __launch_bounds__(256) void k_h2i(int L) {
    int m = blockIdx.x;                 // 0..255
    int b = m >> 1;
    int t = m & 1;
    int s = g_sel[b];
    int p = s - 1 + t;
    bool valid = t == 0 ? (s >= 1) : (s <= L - 3);
    if (!valid) return;
    int physL = g_ord[b * SS + p];
    const float* g = g_g2 + (size_t)m * G4;
    __shared__ float red[256];
    float part = 0.f;
    for (int e = threadIdx.x; e < EE; e += 256) {
        float c = sigm(g[512 + e]) * g_c1[(size_t)physL * EE + e] + sigm(g[e]) * tanhf(g[1024 + e]);
        float h = sigm(g[1536 + e]) * tanhf(c);
        g_h2[(size_t)physL * EE + e] = h;
        part += h * g_fcw[e];
    }
    red[threadIdx.x] = part;
    __syncthreads();
    for (int ss = 128; ss > 0; ss >>= 1) {
        if (threadIdx.x < ss) red[threadIdx.x] += red[threadIdx.x + ss];
        __syncthreads();
    }
    if (threadIdx.x == 0) g_sc[b * SS + p] = sigm(red[0] + g_fcw[EE]);
}

// ================= fused softmax + entropy + merged + ord-update (+final output) =================
__global__ __launch_bounds__(512) void k_smu(int col, int finalFlag, int L,
                                             const float* __restrict__ emb, float* __restrict__ out) {
    int b = blockIdx.x;
    int t = threadIdx.x;      // 0..511
    __shared__ float sh[512];
    __shared__ float srow[NSC];
    __shared__ float s_p500;
    const float* su = g_su + (size_t)b * NSU;
    int s = g_sel[b];
    int phys = g_ord[b * SS + s];
    const float* h2row = g_h2 + (size_t)phys * EE;
    const float isq = 0.044194173824159216f;   // 1/sqrt(512)

    float hv = h2row[t];
    sh[t] = hv * (su[RR + t] + g_v1[t]);
    __syncthreads();
    for (int ss = 256; ss > 0; ss >>= 1) { if (t < ss) sh[t] += sh[t + ss]; __syncthreads(); }
    if (t == 0) srow[RR] = (sh[0] + g_c0[0]) * isq;
    __syncthreads();
    if (t < RR) srow[t] = su[t] * isq;
    __syncthreads();
    float mx = (t < NSC) ? srow[t] : -1e30f;
    sh[t] = mx; __syncthreads();
    for (int ss = 256; ss > 0; ss >>= 1) { if (t < ss) sh[t] = fmaxf(sh[t], sh[t + ss]); __syncthreads(); }
    mx = sh[0]; __syncthreads();
    float zp = (t < NSC) ? expf(srow[t] - mx) : 0.f;
    sh[t] = zp; __syncthreads();
    for (int ss = 256; ss > 0; ss >>= 1) { if (t < ss) sh[t] += sh[t + ss]; __syncthreads(); }
    float lse = mx + logf(sh[0]);
    __syncthreads();
    float p = (t < NSC) ? expf(srow[t] - lse) : 0.f;
    float ep = (t < NSC) ? p * (lse - srow[t]) : 0.f;
    if (finalFlag && t < NSC) out[(size_t)b * NSC + t] = srow[t];
    sh[t] = ep; __syncthreads();
    for (int ss = 256; ss > 0; ss >>= 1) { if (t < ss) sh[t] += sh[t + ss]; __syncthreads(); }
    if (finalFlag) {
        if (t < 16) {
            float v = (t == 15) ? sh[0] : ((t == 14) ? 0.f : g_ent[b * SS + t]);
            out[OUT0 + b * 16 + t] = v;
        }
        return;
    }
    if (t == 0) g_ent[b * SS + col] = sh[0];

    __syncthreads();
    if (t < NSC) srow[t] = p;            // prob in place
    if (t == RR) s_p500 = p;
    __syncthreads();
    float macc = 0.f;
    #pragma unroll 4
    for (int k = 0; k < RR; k++) macc += srow[k] * emb[(size_t)k * EE + t];
    g_cur[(size_t)phys * EE + t] = macc + s_p500 * hv;
    if (t == 0) {
        // logical remap: drop element s+1; merged stays at logical s (same phys row)
        for (int j = s + 1; j <= L - 2; j++) g_ord[b * SS + j] = g_ord[b * SS + j + 1];
        for (int pp = s + 1; pp <= L - 3; pp++) g_sc[b * SS + pp] = g_sc[b * SS + pp + 1];
    }
}

// ================= host launch =================
extern "C" void kernel_launch(void* const* d_in, const int* in_sizes, int n_in,
                              void* d_out, int out_size, void* d_ws, size_t ws_size,
                              hipStream_t stream) {
    const int*   tokens = (const int*)d_in[0];
    const float* emb    = (const float*)d_in[1];
    const float* wih    = (const float*)d_in[2];
    const float* whh    = (const float*)d_in[3];
    const float* bih    = (const float*)d_in[4];
    const float* bhh    = (const float*)d_in[5];
    const float* fcwv   = (const float*)d_in[6];
    const float* fcbv   = (const float*)d_in[7];
    const float* fcqw   = (const float*)d_in[8];
    const float* fcqb   = (const float*)d_in[9];
    const float* fckw   = (const float*)d_in[10];
    const float* fckb   = (const float*)d_in[11];
    float* out = (float*)d_out;

    auto grid32 = [](int M, int N) { return dim3((unsigned)((N + TN - 1) / TN), (unsigned)((M + TM - 1) / TM)); };

    // ---- setup + attention precomputes (once) ----
    k_prep<<<dim3(8), dim3(256), 0, stream>>>(bih, bhh, fcwv, fcbv, fcqb, fckb);
    kg_Krel<<<grid32(RR, EE), dim3(256), 0, stream>>>(emb, fckw);
    k_tr<<<dim3((EE * EE + 255) / 256), dim3(256), 0, stream>>>(fckw);
    kg_W2<<<grid32(RR, EE), dim3(256), 0, stream>>>(fcqw);
    kg_Mx<<<grid32(EE, EE), dim3(256), 0, stream>>>(fcqw);
    k_vprep<<<dim3(502), dim3(512), 0, stream>>>(fcqw, fckw);
    k_gather<<<dim3((BB * SS * EE + 255) / 256), dim3(256), 0, stream>>>(tokens, emb);

    // ---- initial full LSTM pass (once; identity order) ----
    kg_G<<<grid32(BB * SS, G4), dim3(256), 0, stream>>>(wih);
    k_h1<<<dim3((BB * SS * EE + 255) / 256), dim3(256), 0, stream>>>();
    kg_g2<<<grid32(NPAIR, G4), dim3(256), 0, stream>>>(whh);
    k_h2<<<dim3(NPAIR), dim3(256), 0, stream>>>();

    for (int L = SS; L >= 3; L--) {
        kg_su<<<grid32(BB, NSU), dim3(256), 0, stream>>>(L - 1);
        k_smu<<<dim3(BB), dim3(512), 0, stream>>>(SS - L, 0, L, emb, out);
        kg_Gi<<<grid32(BB, G4), dim3(256), 0, stream>>>(wih);
        k_h1i<<<dim3((BB * EE + 255) / 256), dim3(256), 0, stream>>>();
        kg_g2i<<<grid32(2 * BB, G4), dim3(256), 0, stream>>>(whh);
        k_h2i<<<dim3(2 * BB), dim3(256), 0, stream>>>(L);
    }

    // L == 2: pair 0's h2 is the final x; final k_smu writes scores + loss region
    kg_su<<<grid32(BB, NSU), dim3(256), 0, stream>>>(1);
    k_smu<<<dim3(BB), dim3(512), 0, stream>>>(15, 1, 2, emb, out);

    (void)in_sizes; (void)n_in; (void)out_size; (void)d_ws; (void)ws_size;
}

// Round 16
// 2046.375 us; speedup vs baseline: 1.5087x; 1.2240x over previous
//
#include <hip/hip_runtime.h>
#include <hip/hip_bf16.h>

#define BB 128
#define SS 16
#define EE 512
#define RR 500
#define G4 2048          // 4*E
#define OUT0 64128       // B*501 : scores chunk first
#define NSC 501          // R+1
#define NPAIR 2047       // init pair rows m=0..2046 (p==15 junk, never read)
#define NSU 1012         // 500 scores | 512 u

__device__ __forceinline__ float sigm(float x) { return 1.f / (1.f + expf(-x)); }

// ================= device-global pipeline buffers =================
__device__ float g_blstm[G4];
__device__ float g_fcw[EE + 4];          // fc_w, fc_b at [EE]
__device__ float g_qbias[1024];          // fcq_b | fck_b
__device__ float g_Krel[RR * EE];
__device__ float g_cur[BB * SS * EE];    // physical rows, never shifted
__device__ float g_G[BB * SS * G4];
__device__ float g_h1[BB * SS * EE];
__device__ float g_c1[BB * SS * EE];
__device__ float g_h2[BB * SS * EE];     // pair keyed by physical row of left elem
__device__ float g_g2[BB * SS * G4];     // init scratch; first 256 rows reused per-iter
__device__ float g_sc[BB * SS];          // LOGICAL pair index
__device__ float g_ent[BB * SS];
__device__ int   g_sel[BB];
__device__ int   g_ord[BB * SS];         // logical pos -> physical row
// attention precomputes + fused buffers
__device__ float g_fckwT[EE * EE];
__device__ float g_W2[RR * EE];
__device__ float g_Mx[EE * EE];
__device__ float g_c2[RR + 4];
__device__ float g_v1[EE];
__device__ float g_c0[1];
__device__ float g_su[BB * NSU];

// ================= setup =================
__global__ void k_prep(const float* __restrict__ bih, const float* __restrict__ bhh,
                       const float* __restrict__ fcwv, const float* __restrict__ fcbv,
                       const float* __restrict__ fcqb, const float* __restrict__ fckb) {
    int i = blockIdx.x * blockDim.x + threadIdx.x;   // 2048
    if (i < G4) g_blstm[i] = bih[i] + bhh[i];
    if (i < EE) {
        g_fcw[i] = fcwv[i];
        g_qbias[i] = fcqb[i];
        g_qbias[EE + i] = fckb[i];
    }
    if (i == 0) g_fcw[EE] = fcbv[0];
    if (i < BB * SS) g_ord[i] = i;
}

__global__ void k_gather(const int* __restrict__ tok, const float* __restrict__ emb) {
    int i = blockIdx.x * blockDim.x + threadIdx.x;
    if (i >= BB * SS * EE) return;
    int e = i & (EE - 1);
    int r = i >> 9;
    int t = tok[r];
    g_cur[i] = emb[(size_t)t * EE + e];
}

__global__ void k_tr(const float* __restrict__ fckw) {
    int i = blockIdx.x * blockDim.x + threadIdx.x;   // 512*512
    if (i >= EE * EE) return;
    int ep = i >> 9;
    int f = i & (EE - 1);
    g_fckwT[(size_t)f * EE + ep] = fckw[(size_t)ep * EE + f];
}

__global__ __launch_bounds__(512) void k_vprep(const float* __restrict__ fcqw, const float* __restrict__ fckw) {
    __shared__ float sh[512];
    int t = threadIdx.x;
    int blk = blockIdx.x;
    if (blk == 0) {
        float acc = 0.f;
        for (int ep = 0; ep < EE; ep++)
            acc += g_qbias[ep] * fckw[(size_t)ep * EE + t] + g_qbias[EE + ep] * fcqw[(size_t)ep * EE + t];
        g_v1[t] = acc;
    } else if (blk == 1) {
        sh[t] = g_qbias[t] * g_qbias[EE + t];
        __syncthreads();
        for (int s = 256; s > 0; s >>= 1) { if (t < s) sh[t] += sh[t + s]; __syncthreads(); }
        if (t == 0) g_c0[0] = sh[0];
    } else {
        int k = blk - 2;
        sh[t] = g_Krel[(size_t)k * EE + t] * g_qbias[t];
        __syncthreads();
        for (int s = 256; s > 0; s >>= 1) { if (t < s) sh[t] += sh[t + s]; __syncthreads(); }
        if (t == 0) g_c2[k] = sh[0];
    }
}

// ================= fp32 GEMM tile core: K-major LDS, vectorized reads =================
#define TM 32
#define TN 64
#define TK 32
__device__ __forceinline__ void gemm_dev(
    const float* __restrict__ A, int lda,
    const float* __restrict__ W, int ldw, int wtrans,
    const float* __restrict__ bias, const float* __restrict__ Dadd, int ldd,
    float* __restrict__ C, int ldc, int M, int N, int K)
{
    __shared__ __align__(16) float As[TK][TM + 2];   // row stride 136 B (8B mult)
    __shared__ __align__(16) float Ws[TK][TN + 4];   // row stride 272 B (16B mult)
    int tid = threadIdx.x;
    int mt = blockIdx.y * TM;
    int nt = blockIdx.x * TN;
    int tr = tid >> 4;
    int tc = tid & 15;
    float acc[2][4] = {{0.f,0.f,0.f,0.f},{0.f,0.f,0.f,0.f}};

    int ea = tid * 4;
    int ra = ea >> 5;
    int ka = ea & 31;
    int gmA = mt + ra;
    bool rokA = gmA < M;
    int ew = tid * 8;
    int rw = ew >> 5;
    int kw = ew & 31;
    int gnW = nt + rw;
    bool rokW = gnW < N;

    for (int kt = 0; kt < K; kt += TK) {
        #pragma unroll
        for (int i = 0; i < 4; i++) {
            int gk = kt + ka + i;
            float v = 0.f;
            if (rokA && gk < K) v = A[(size_t)gmA * lda + gk];
            As[ka + i][ra] = v;
        }
        #pragma unroll
        for (int i = 0; i < 8; i++) {
            int gk = kt + kw + i;
            float v = 0.f;
            if (rokW && gk < K)
                v = wtrans ? W[(size_t)gk * ldw + gnW] : W[(size_t)gnW * ldw + gk];
            Ws[kw + i][rw] = v;
        }
        __syncthreads();
        #pragma unroll
        for (int kk = 0; kk < TK; kk++) {
            const float2 a = *(const float2*)&As[kk][2 * tr];
            const float4 w = *(const float4*)&Ws[kk][4 * tc];
            acc[0][0] += a.x * w.x; acc[0][1] += a.x * w.y; acc[0][2] += a.x * w.z; acc[0][3] += a.x * w.w;
            acc[1][0] += a.y * w.x; acc[1][1] += a.y * w.y; acc[1][2] += a.y * w.z; acc[1][3] += a.y * w.w;
        }
        __syncthreads();
    }
    #pragma unroll
    for (int i = 0; i < 2; i++) {
        int gm = mt + 2 * tr + i;
        if (gm >= M) continue;
        #pragma unroll
        for (int j = 0; j < 4; j++) {
            int gn = nt + 4 * tc + j;
            if (gn >= N) continue;
            float v = (i == 0) ? ((j == 0) ? acc[0][0] : (j == 1) ? acc[0][1] : (j == 2) ? acc[0][2] : acc[0][3])
                               : ((j == 0) ? acc[1][0] : (j == 1) ? acc[1][1] : (j == 2) ? acc[1][2] : acc[1][3]);
            if (bias) v += bias[gn];
            if (Dadd) v += Dadd[(size_t)gm * ldd + gn];
            C[(size_t)gm * ldc + gn] = v;
        }
    }
}

// ---- full GEMM wrappers ----
__global__ __launch_bounds__(256) void kg_Krel(const float* __restrict__ emb, const float* __restrict__ fckw) {
    gemm_dev(emb, EE, fckw, EE, 0, g_qbias + EE, nullptr, 0, g_Krel, EE, RR, EE, EE);
}
__global__ __launch_bounds__(256) void kg_W2(const float* __restrict__ fcqw) {
    gemm_dev(g_Krel, EE, fcqw, EE, 1, nullptr, nullptr, 0, g_W2, EE, RR, EE, EE);
}
__global__ __launch_bounds__(256) void kg_Mx(const float* __restrict__ fcqw) {
    gemm_dev(g_fckwT, EE, fcqw, EE, 1, nullptr, nullptr, 0, g_Mx, EE, EE, EE, EE);
}
__global__ __launch_bounds__(256) void kg_G(const float* __restrict__ wih) {
    gemm_dev(g_cur, EE, wih, EE, 0, g_blstm, nullptr, 0, g_G, G4, BB * SS, G4, EE);
}
__global__ __launch_bounds__(256) void kg_g2(const float* __restrict__ whh) {
    gemm_dev(g_h1, EE, whh, EE, 0, nullptr, g_G + G4, G4, g_g2, G4, NPAIR, G4, EE);
}

// ---- fused argmax + scores|u GEMM ----
__global__ __launch_bounds__(256) void kg_su(int P) {
    __shared__ __align__(16) float As[TK][TM + 2];
    __shared__ __align__(16) float Ws[TK][TN + 4];
    __shared__ int s_phys[TM];
    int tid = threadIdx.x;
    int mt = blockIdx.y * TM;
    int nt = blockIdx.x * TN;
    int tr = tid >> 4;
    int tc = tid & 15;
    float acc[2][4] = {{0.f,0.f,0.f,0.f},{0.f,0.f,0.f,0.f}};

    if (tid < TM) {
        int b = mt + tid;                    // M = BB exact
        float best = -1e30f; int bi = 0;
        for (int p = 0; p < P; p++) {
            float v = g_sc[b * SS + p];
            if (v > best) { best = v; bi = p; }
        }
        s_phys[tid] = g_ord[b * SS + bi];
        if (blockIdx.x == 0) g_sel[b] = bi;
    }
    __syncthreads();

    int ea = tid * 4;
    int ra = ea >> 5;
    int ka = ea & 31;
    int physA = s_phys[ra];
    int ew = tid * 8;
    int rw = ew >> 5;
    int kw = ew & 31;
    int gnW = nt + rw;
    bool rokW = gnW < NSU;
    const float* Wrow = nullptr;
    if (rokW) Wrow = (gnW < RR) ? (g_W2 + (size_t)gnW * EE) : (g_Mx + (size_t)(gnW - RR) * EE);

    for (int kt = 0; kt < EE; kt += TK) {
        #pragma unroll
        for (int i = 0; i < 4; i++)
            As[ka + i][ra] = g_h2[(size_t)physA * EE + kt + ka + i];
        #pragma unroll
        for (int i = 0; i < 8; i++)
            Ws[kw + i][rw] = rokW ? Wrow[kt + kw + i] : 0.f;
        __syncthreads();
        #pragma unroll
        for (int kk = 0; kk < TK; kk++) {
            const float2 a = *(const float2*)&As[kk][2 * tr];
            const float4 w = *(const float4*)&Ws[kk][4 * tc];
            acc[0][0] += a.x * w.x; acc[0][1] += a.x * w.y; acc[0][2] += a.x * w.z; acc[0][3] += a.x * w.w;
            acc[1][0] += a.y * w.x; acc[1][1] += a.y * w.y; acc[1][2] += a.y * w.z; acc[1][3] += a.y * w.w;
        }
        __syncthreads();
    }
    #pragma unroll
    for (int i = 0; i < 2; i++) {
        int gm = mt + 2 * tr + i;
        #pragma unroll
        for (int j = 0; j < 4; j++) {
            int gn = nt + 4 * tc + j;
            if (gn >= NSU) continue;
            float v = (i == 0) ? ((j == 0) ? acc[0][0] : (j == 1) ? acc[0][1] : (j == 2) ? acc[0][2] : acc[0][3])
                               : ((j == 0) ? acc[1][0] : (j == 1) ? acc[1][1] : (j == 2) ? acc[1][2] : acc[1][3]);
            g_su[(size_t)gm * NSU + gn] = v + (gn < RR ? g_c2[gn] : 0.f);
        }
    }
}

// ---- incremental GEMM: G[ord[sel]]; M=BB ----
__global__ __launch_bounds__(256) void kg_Gi(const float* __restrict__ wih) {
    __shared__ __align__(16) float As[TK][TM + 2];
    __shared__ __align__(16) float Ws[TK][TN + 4];
    __shared__ int s_phys[TM];
    int tid = threadIdx.x;
    int mt = blockIdx.y * TM;
    int nt = blockIdx.x * TN;
    int tr = tid >> 4;
    int tc = tid & 15;
    float acc[2][4] = {{0.f,0.f,0.f,0.f},{0.f,0.f,0.f,0.f}};

    if (tid < TM) {
        int b = mt + tid;
        s_phys[tid] = g_ord[b * SS + g_sel[b]];
    }
    __syncthreads();

    int ea = tid * 4;
    int ra = ea >> 5;
    int ka = ea & 31;
    int physA = s_phys[ra];
    int ew = tid * 8;
    int rw = ew >> 5;
    int kw = ew & 31;
    int gnW = nt + rw;

    for (int kt = 0; kt < EE; kt += TK) {
        #pragma unroll
        for (int i = 0; i < 4; i++)
            As[ka + i][ra] = g_cur[(size_t)physA * EE + kt + ka + i];
        #pragma unroll
        for (int i = 0; i < 8; i++)
            Ws[kw + i][rw] = wih[(size_t)gnW * EE + kt + kw + i];
        __syncthreads();
        #pragma unroll
        for (int kk = 0; kk < TK; kk++) {
            const float2 a = *(const float2*)&As[kk][2 * tr];
            const float4 w = *(const float4*)&Ws[kk][4 * tc];
            acc[0][0] += a.x * w.x; acc[0][1] += a.x * w.y; acc[0][2] += a.x * w.z; acc[0][3] += a.x * w.w;
            acc[1][0] += a.y * w.x; acc[1][1] += a.y * w.y; acc[1][2] += a.y * w.z; acc[1][3] += a.y * w.w;
        }
        __syncthreads();
    }
    #pragma unroll
    for (int i = 0; i < 2; i++) {
        int phys = s_phys[2 * tr + i];
        #pragma unroll
        for (int j = 0; j < 4; j++) {
            int gn = nt + 4 * tc + j;
            float v = (i == 0) ? ((j == 0) ? acc[0][0] : (j == 1) ? acc[0][1] : (j == 2) ? acc[0][2] : acc[0][3])
                               : ((j == 0) ? acc[1][0] : (j == 1) ? acc[1][1] : (j == 2) ? acc[1][2] : acc[1][3]);
            g_G[(size_t)phys * G4 + gn] = v + g_blstm[gn];
        }
    }
}

// ---- incremental h1/c1 for the merged row ----
__global__ void k_h1i() {
    int idx = blockIdx.x * blockDim.x + threadIdx.x;   // BB*EE
    if (idx >= BB * EE) return;
    int b = idx >> 9;
    int e = idx & (EE - 1);
    int phys = g_ord[b * SS + g_sel[b]];
    const float* g = g_G + (size_t)phys * G4;
    float c = sigm(g[e]) * tanhf(g[1024 + e]);
    g_c1[(size_t)phys * EE + e] = c;
    g_h1[(size_t)phys * EE + e] = sigm(g[1536 + e]) * tanhf(c);
}

// ---- incremental GEMM: g2 for 2 candidate pairs/batch; M=2*BB ----
__global__ __launch_bounds__(256) void kg_g2i(const float* __restrict__ whh) {
    __shared__ __align__(16) float As[TK][TM + 2];
    __shared__ __align__(16) float Ws[TK][TN + 4];
    __shared__ int s_physA[TM];
    __shared__ int s_physD[TM];
    int tid = threadIdx.x;
    int mt = blockIdx.y * TM;
    int nt = blockIdx.x * TN;
    int tr = tid >> 4;
    int tc = tid & 15;
    float acc[2][4] = {{0.f,0.f,0.f,0.f},{0.f,0.f,0.f,0.f}};

    if (tid < TM) {
        int gm = mt + tid;
        int b = gm >> 1;
        int p = min(max(g_sel[b] - 1 + (gm & 1), 0), 14);
        s_physA[tid] = g_ord[b * SS + p];
        s_physD[tid] = g_ord[b * SS + p + 1];
    }
    __syncthreads();

    int ea = tid * 4;
    int ra = ea >> 5;
    int ka = ea & 31;
    int physA = s_physA[ra];
    int ew = tid * 8;
    int rw = ew >> 5;
    int kw = ew & 31;
    int gnW = nt + rw;

    for (int kt = 0; kt < EE; kt += TK) {
        #pragma unroll
        for (int i = 0; i < 4; i++)
            As[ka + i][ra] = g_h1[(size_t)physA * EE + kt + ka + i];
        #pragma unroll
        for (int i = 0; i < 8; i++)
            Ws[kw + i][rw] = whh[(size_t)gnW * EE + kt + kw + i];
        __syncthreads();
        #pragma unroll
        for (int kk = 0; kk < TK; kk++) {
            const float2 a = *(const float2*)&As[kk][2 * tr];
            const float4 w = *(const float4*)&Ws[kk][4 * tc];
            acc[0][0] += a.x * w.x; acc[0][1] += a.x * w.y; acc[0][2] += a.x * w.z; acc[0][3] += a.x * w.w;
            acc[1][0] += a.y * w.x; acc[1][1] += a.y * w.y; acc[1][2] += a.y * w.z; acc[1][3] += a.y * w.w;
        }
        __syncthreads();
    }
    #pragma unroll
    for (int i = 0; i < 2; i++) {
        int gm = mt + 2 * tr + i;
        size_t drow = (size_t)s_physD[2 * tr + i] * G4;
        #pragma unroll
        for (int j = 0; j < 4; j++) {
            int gn = nt + 4 * tc + j;
            float v = (i == 0) ? ((j == 0) ? acc[0][0] : (j == 1) ? acc[0][1] : (j == 2) ? acc[0][2] : acc[0][3])
                               : ((j == 0) ? acc[1][0] : (j == 1) ? acc[1][1] : (j == 2) ? acc[1][2] : acc[1][3]);
            g_g2[(size_t)gm * G4 + gn] = v + g_G[drow + gn];
        }
    }
}

// ================= LSTM elementwise (init) =================
__global__ void k_h1() {
    int idx = blockIdx.x * blockDim.x + threadIdx.x;
    if (idx >= BB * SS * EE) return;
    int m = idx >> 9;
    int e = idx & (EE - 1);
    const float* g = g_G + (size_t)m * G4;
    float c = sigm(g[e]) * tanhf(g[1024 + e]);
    g_c1[idx] = c;
    g_h1[idx] = sigm(g[1536 + e]) * tanhf(c);
}

__global__ __launch_bounds__(256) void k_h2() {
    int m = blockIdx.x;                 // 0..2046 (identity order at init)
    const float* g = g_g2 + (size_t)m * G4;
    __shared__ float red[256];
    float part = 0.f;
    for (int e = threadIdx.x; e < EE; e += 256) {
        float c = sigm(g[512 + e]) * g_c1[(size_t)m * EE + e] + sigm(g[e]) * tanhf(g[1024 + e]);
        float h = sigm(g[1536 + e]) * tanhf(c);
        g_h2[(size_t)m * EE + e] = h;
        part += h * g_fcw[e];
    }
    red[threadIdx.x] = part;
    __syncthreads();
    for (int s = 128; s > 0; s >>= 1) {
        if (threadIdx.x < s) red[threadIdx.x] += red[threadIdx.x + s];
        __syncthreads();
    }
    if (threadIdx.x == 0) g_sc[m] = sigm(red[0] + g_fcw[EE]);
}

// per-iter h2/sc for the 2 candidate pairs
__global__ __launch_bounds__(256) void k_h2i(int L) {
    int m = blockIdx.x;                 // 0..255
    int b = m >> 1;
    int t = m & 1;
    int s = g_sel[b];
    int p = s - 1 + t;
    bool valid = t == 0 ? (s >= 1) : (s <= L - 3);
    if (!valid) return;
    int physL = g_ord[b * SS + p];
    const float* g = g_g2 + (size_t)m * G4;
    __shared__ float red[256];
    float part = 0.f;
    for (int e = threadIdx.x; e < EE; e += 256) {
        float c = sigm(g[512 + e]) * g_c1[(size_t)physL * EE + e] + sigm(g[e]) * tanhf(g[1024 + e]);
        float h = sigm(g[1536 + e]) * tanhf(c);
        g_h2[(size_t)physL * EE + e] = h;
        part += h * g_fcw[e];
    }
    red[threadIdx.x] = part;
    __syncthreads();
    for (int ss = 128; ss > 0; ss >>= 1) {
        if (threadIdx.x < ss) red[threadIdx.x] += red[threadIdx.x + ss];
        __syncthreads();
    }
    if (threadIdx.x == 0) g_sc[b * SS + p] = sigm(red[0] + g_fcw[EE]);
}

// ================= fused softmax + entropy + merged + ord-update (+final output) =================
__global__ __launch_bounds__(512) void k_smu(int col, int finalFlag, int L,
                                             const float* __restrict__ emb, float* __restrict__ out) {
    int b = blockIdx.x;
    int t = threadIdx.x;      // 0..511
    __shared__ float sh[512];
    __shared__ float srow[NSC];
    __shared__ float s_p500;
    const float* su = g_su + (size_t)b * NSU;
    int s = g_sel[b];
    int phys = g_ord[b * SS + s];
    const float* h2row = g_h2 + (size_t)phys * EE;
    const float isq = 0.044194173824159216f;   // 1/sqrt(512)

    float hv = h2row[t];
    sh[t] = hv * (su[RR + t] + g_v1[t]);
    __syncthreads();
    for (int ss = 256; ss > 0; ss >>= 1) { if (t < ss) sh[t] += sh[t + ss]; __syncthreads(); }
    if (t == 0) srow[RR] = (sh[0] + g_c0[0]) * isq;
    __syncthreads();
    if (t < RR) srow[t] = su[t] * isq;
    __syncthreads();
    float mx = (t < NSC) ? srow[t] : -1e30f;
    sh[t] = mx; __syncthreads();
    for (int ss = 256; ss > 0; ss >>= 1) { if (t < ss) sh[t] = fmaxf(sh[t], sh[t + ss]); __syncthreads(); }
    mx = sh[0]; __syncthreads();
    float zp = (t < NSC) ? expf(srow[t] - mx) : 0.f;
    sh[t] = zp; __syncthreads();
    for (int ss = 256; ss > 0; ss >>= 1) { if (t < ss) sh[t] += sh[t + ss]; __syncthreads(); }
    float lse = mx + logf(sh[0]);
    __syncthreads();
    float p = (t < NSC) ? expf(srow[t] - lse) : 0.f;
    float ep = (t < NSC) ? p * (lse - srow[t]) : 0.f;
    if (finalFlag && t < NSC) out[(size_t)b * NSC + t] = srow[t];
    sh[t] = ep; __syncthreads();
    for (int ss = 256; ss > 0; ss >>= 1) { if (t < ss) sh[t] += sh[t + ss]; __syncthreads(); }
    if (finalFlag) {
        if (t < 16) {
            float v = (t == 15) ? sh[0] : ((t == 14) ? 0.f : g_ent[b * SS + t]);
            out[OUT0 + b * 16 + t] = v;
        }
        return;
    }
    if (t == 0) g_ent[b * SS + col] = sh[0];

    __syncthreads();
    if (t < NSC) srow[t] = p;
    if (t == RR) s_p500 = p;
    __syncthreads();
    float macc = 0.f;
    #pragma unroll 4
    for (int k = 0; k < RR; k++) macc += srow[k] * emb[(size_t)k * EE + t];
    g_cur[(size_t)phys * EE + t] = macc + s_p500 * hv;
    if (t == 0) {
        for (int j = s + 1; j <= L - 2; j++) g_ord[b * SS + j] = g_ord[b * SS + j + 1];
        for (int pp = s + 1; pp <= L - 3; pp++) g_sc[b * SS + pp] = g_sc[b * SS + pp + 1];
    }
}

// ================= host launch =================
extern "C" void kernel_launch(void* const* d_in, const int* in_sizes, int n_in,
                              void* d_out, int out_size, void* d_ws, size_t ws_size,
                              hipStream_t stream) {
    const int*   tokens = (const int*)d_in[0];
    const float* emb    = (const float*)d_in[1];
    const float* wih    = (const float*)d_in[2];
    const float* whh    = (const float*)d_in[3];
    const float* bih    = (const float*)d_in[4];
    const float* bhh    = (const float*)d_in[5];
    const float* fcwv   = (const float*)d_in[6];
    const float* fcbv   = (const float*)d_in[7];
    const float* fcqw   = (const float*)d_in[8];
    const float* fcqb   = (const float*)d_in[9];
    const float* fckw   = (const float*)d_in[10];
    const float* fckb   = (const float*)d_in[11];
    float* out = (float*)d_out;

    auto grid32 = [](int M, int N) { return dim3((unsigned)((N + TN - 1) / TN), (unsigned)((M + TM - 1) / TM)); };

    // ---- setup + attention precomputes (once) ----
    k_prep<<<dim3(8), dim3(256), 0, stream>>>(bih, bhh, fcwv, fcbv, fcqb, fckb);
    kg_Krel<<<grid32(RR, EE), dim3(256), 0, stream>>>(emb, fckw);
    k_tr<<<dim3((EE * EE + 255) / 256), dim3(256), 0, stream>>>(fckw);
    kg_W2<<<grid32(RR, EE), dim3(256), 0, stream>>>(fcqw);
    kg_Mx<<<grid32(EE, EE), dim3(256), 0, stream>>>(fcqw);
    k_vprep<<<dim3(502), dim3(512), 0, stream>>>(fcqw, fckw);
    k_gather<<<dim3((BB * SS * EE + 255) / 256), dim3(256), 0, stream>>>(tokens, emb);

    // ---- initial full LSTM pass (once; identity order) ----
    kg_G<<<grid32(BB * SS, G4), dim3(256), 0, stream>>>(wih);
    k_h1<<<dim3((BB * SS * EE + 255) / 256), dim3(256), 0, stream>>>();
    kg_g2<<<grid32(NPAIR, G4), dim3(256), 0, stream>>>(whh);
    k_h2<<<dim3(NPAIR), dim3(256), 0, stream>>>();

    for (int L = SS; L >= 3; L--) {
        kg_su<<<grid32(BB, NSU), dim3(256), 0, stream>>>(L - 1);
        k_smu<<<dim3(BB), dim3(512), 0, stream>>>(SS - L, 0, L, emb, out);
        kg_Gi<<<grid32(BB, G4), dim3(256), 0, stream>>>(wih);
        k_h1i<<<dim3((BB * EE + 255) / 256), dim3(256), 0, stream>>>();
        kg_g2i<<<grid32(2 * BB, G4), dim3(256), 0, stream>>>(whh);
        k_h2i<<<dim3(2 * BB), dim3(256), 0, stream>>>(L);
    }

    // L == 2: pair 0's h2 is the final x; final k_smu writes scores + loss region
    kg_su<<<grid32(BB, NSU), dim3(256), 0, stream>>>(1);
    k_smu<<<dim3(BB), dim3(512), 0, stream>>>(15, 1, 2, emb, out);

    (void)in_sizes; (void)n_in; (void)out_size; (void)d_ws; (void)ws_size;
}